// Round 3
// baseline (1066.883 us; speedup 1.0000x reference)
//
#include <hip/hip_runtime.h>
#include <hip/hip_bf16.h>
#include <math.h>

// Problem constants (Arctic decoder layer)
#define B_    2
#define S_    1024
#define H_    1024
#define NH_   16
#define NKV_  4
#define HD_   64
#define F_    2816
#define E_    8
#define WIN_  256
#define T_    (B_*S_)
#define EPS_  1e-5f
#define QKVN_ 1536

typedef __hip_bfloat16 bf16;
using f32x4  = __attribute__((ext_vector_type(4))) float;
using bf16x8 = __attribute__((ext_vector_type(8))) short;

__device__ __forceinline__ float silu_f(float x) { return x / (1.0f + expf(-x)); }

__device__ __forceinline__ unsigned short f2bf(float v) {
  __hip_bfloat16 b = __float2bfloat16(v);
  return *reinterpret_cast<unsigned short*>(&b);
}

// async global->LDS 16B stage (linear LDS dst: wave-uniform base + lane*16)
__device__ __forceinline__ void stage16(const void* g, void* l) {
#if defined(__has_builtin) && __has_builtin(__builtin_amdgcn_global_load_lds)
  __builtin_amdgcn_global_load_lds((const __attribute__((address_space(1))) unsigned int*)g,
                                   (__attribute__((address_space(3))) unsigned int*)l,
                                   16, 0, 0);
#else
  *(float4*)l = *(const float4*)g;
#endif
}

// ---------------- zero counts ----------------
__global__ void zero_counts_kernel(int* counts) {
  if (threadIdx.x < E_) counts[threadIdx.x] = 0;
}

// ---------------- RoPE tables ----------------
__global__ void rope_table_kernel(float* __restrict__ costab, float* __restrict__ sintab) {
  int idx = blockIdx.x * blockDim.x + threadIdx.x;  // S_*32
  if (idx >= S_ * 32) return;
  int s = idx >> 5, j = idx & 31;
  float inv = powf(10000.0f, -(float)j / 32.0f);
  float ang = (float)s * inv;
  costab[idx] = cosf(ang);
  sintab[idx] = sinf(ang);
}

// ---------------- transpose + fp32->bf16: src[K][N] -> dst[N][K] ----------------
__global__ void transpose_cvt_kernel(const float* __restrict__ src, bf16* __restrict__ dst,
                                     int K, int N) {
  __shared__ float tile[32][33];
  const size_t bstride = (size_t)K * N;
  src += bstride * blockIdx.z;
  dst += bstride * blockIdx.z;
  int bk = blockIdx.x * 32, bn = blockIdx.y * 32;
  int tx = threadIdx.x & 31, ty = threadIdx.x >> 5;  // 256 thr: ty 0..7
  #pragma unroll
  for (int i = 0; i < 4; ++i)
    tile[ty + i * 8][tx] = src[(size_t)(bk + ty + i * 8) * N + bn + tx];
  __syncthreads();
  #pragma unroll
  for (int i = 0; i < 4; ++i)
    dst[(size_t)(bn + ty + i * 8) * K + bk + tx] = __float2bfloat16(tile[tx][ty + i * 8]);
}

// ---------------- RMSNorm: fp32 in -> bf16 out (+ optional fp32 out) ----------------
template <bool EMIT_F32>
__global__ void rms_kernel(const float* __restrict__ x, const float* __restrict__ w,
                           bf16* __restrict__ ob, float* __restrict__ of) {
  const int row = blockIdx.x, t = threadIdx.x;  // 256
  const float* xr = x + (size_t)row * H_;
  float4 v = *(const float4*)(&xr[t * 4]);
  float ss = v.x*v.x + v.y*v.y + v.z*v.z + v.w*v.w;
  #pragma unroll
  for (int o = 32; o > 0; o >>= 1) ss += __shfl_xor(ss, o);
  __shared__ float red[4];
  if ((t & 63) == 0) red[t >> 6] = ss;
  __syncthreads();
  float tot = red[0] + red[1] + red[2] + red[3];
  float scale = rsqrtf(tot * (1.0f / H_) + EPS_);
  float4 wv = *(const float4*)(&w[t * 4]);
  float o0 = v.x*scale*wv.x, o1 = v.y*scale*wv.y, o2 = v.z*scale*wv.z, o3 = v.w*scale*wv.w;
  ushort4 pk = { f2bf(o0), f2bf(o1), f2bf(o2), f2bf(o3) };
  *(ushort4*)((unsigned short*)ob + (size_t)row * H_ + t * 4) = pk;
  if (EMIT_F32) {
    float4 o4 = {o0, o1, o2, o3};
    *(float4*)(of + (size_t)row * H_ + t * 4) = o4;
  }
}

// =====================================================================
// bf16 MFMA GEMM: C[M,N] = A[M,K](bf16) @ Bt[N,K](bf16)^T (+Res), fp32 out
// 128x128 tile, BK=32, 256 thr (4 waves, 2x2 of 64x64), m97 structure.
// LDS rows = 64B (32 bf16); 16B chunk swizzle: chunk' = chunk ^ ((row>>1)&3).
// =====================================================================
template <bool ADD_RES>
__global__ __launch_bounds__(256)
void mm_kernel(const bf16* __restrict__ A, const bf16* __restrict__ Bt,
               const float* __restrict__ Res, float* __restrict__ C,
               int M, int N, int K) {
  __shared__ char Al[8192];
  __shared__ char Bl[8192];
  const int t = threadIdx.x;
  const int m0 = blockIdx.y * 128, n0 = blockIdx.x * 128;
  const int lane = t & 63, wid = t >> 6;
  const int wr = wid >> 1, wc = wid & 1;
  // staging: thread t covers 16B chunk (row=t>>2, chunk=t&3), second issue at +64 rows
  const int sr = t >> 2, sc = t & 3;
  const int cA0 = sc ^ ((sr >> 1) & 3);
  const int cA1 = sc ^ (((sr + 64) >> 1) & 3);
  const bf16* gA0 = A + (size_t)(m0 + sr) * K + cA0 * 8;
  const bf16* gA1 = A + (size_t)(m0 + sr + 64) * K + cA1 * 8;
  const bf16* gB0 = Bt + (size_t)(n0 + sr) * K + cA0 * 8;
  const bf16* gB1 = Bt + (size_t)(n0 + sr + 64) * K + cA1 * 8;
  char* lA0 = Al + t * 16;
  char* lA1 = Al + 4096 + t * 16;
  char* lB0 = Bl + t * 16;
  char* lB1 = Bl + 4096 + t * 16;
  // fragment read offsets (inverse swizzle on read)
  const int la = lane & 15, kg = lane >> 4;
  const int swz = (kg ^ ((la >> 1) & 3)) * 16;
  const int aoff = (wr * 64 + la) * 64 + swz;
  const int boff = (wc * 64 + la) * 64 + swz;
  f32x4 acc[4][4] = {};
  for (int k0 = 0; k0 < K; k0 += 32) {
    stage16(gA0 + k0, lA0);
    stage16(gA1 + k0, lA1);
    stage16(gB0 + k0, lB0);
    stage16(gB1 + k0, lB1);
    __syncthreads();
    bf16x8 af[4], bf[4];
    #pragma unroll
    for (int i = 0; i < 4; ++i) af[i] = *(const bf16x8*)(Al + aoff + i * 1024);
    #pragma unroll
    for (int i = 0; i < 4; ++i) bf[i] = *(const bf16x8*)(Bl + boff + i * 1024);
    #pragma unroll
    for (int mi = 0; mi < 4; ++mi)
      #pragma unroll
      for (int ni = 0; ni < 4; ++ni)
        acc[mi][ni] = __builtin_amdgcn_mfma_f32_16x16x32_bf16(af[mi], bf[ni], acc[mi][ni], 0, 0, 0);
    __syncthreads();
  }
  #pragma unroll
  for (int mi = 0; mi < 4; ++mi) {
    int row = m0 + wr * 64 + mi * 16 + kg * 4;
    #pragma unroll
    for (int ni = 0; ni < 4; ++ni) {
      int col = n0 + wc * 64 + ni * 16 + la;
      #pragma unroll
      for (int r = 0; r < 4; ++r) {
        size_t off = (size_t)(row + r) * N + col;
        float v = acc[mi][ni][r];
        if (ADD_RES) v += Res[off];
        C[off] = v;
      }
    }
  }
}

// ---------------- RoPE apply (packed QKV, in-place) ----------------
__global__ void rope_apply_kernel(float* __restrict__ x, const float* __restrict__ ct,
                                  const float* __restrict__ st, int nheads, int stride, int total) {
  int idx = blockIdx.x * blockDim.x + threadIdx.x;
  if (idx >= total) return;
  int j = idx & 31;
  int hh = (idx >> 5) % nheads;
  int t = idx / (32 * nheads);
  int s = t & (S_ - 1);
  float c = ct[s * 32 + j], sn = st[s * 32 + j];
  float* bp = x + (size_t)t * stride + hh * HD_;
  float x1 = bp[j], x2 = bp[j + 32];
  bp[j]      = x1 * c - x2 * sn;
  bp[j + 32] = x2 * c + x1 * sn;
}

// ---------------- sliding-window causal attention, wave-parallel ----------------
// 1 wave per (s,h,b). QK: lane owns <=4 keys, Q broadcast from LDS.
// PV: lane owns output dim d=lane, p broadcast from LDS, coalesced V loads.
__global__ void attn_kernel(const float* __restrict__ QKV, bf16* __restrict__ O) {
  const int s = blockIdx.x, h = blockIdx.y, b = blockIdx.z;
  const int lane = threadIdx.x;  // 64
  const int kvh = h >> 2;        // NH/NKV = 4
  __shared__ float q_lds[HD_];
  __shared__ float p_lds[WIN_];
  int k0 = s - (WIN_ - 1); if (k0 < 0) k0 = 0;
  const int nk = s - k0 + 1;
  const size_t rowbase = (size_t)(b * S_ + k0) * QKVN_;
  q_lds[lane] = QKV[(size_t)(b * S_ + s) * QKVN_ + h * HD_ + lane];
  __syncthreads();
  float sc[4];
  float mx = -3.0e38f;
  #pragma unroll
  for (int i = 0; i < 4; ++i) {
    int kk = lane + i * 64;
    float acc = 0.f;
    if (kk < nk) {
      const float* Kr = QKV + rowbase + (size_t)kk * QKVN_ + 1024 + kvh * HD_;
      #pragma unroll
      for (int c = 0; c < 16; ++c) {
        float4 kv = *(const float4*)(Kr + c * 4);
        float4 qv = *(const float4*)(&q_lds[c * 4]);  // broadcast, conflict-free
        acc += kv.x*qv.x + kv.y*qv.y + kv.z*qv.z + kv.w*qv.w;
      }
      acc *= 0.125f;  // HD^-0.5
      mx = fmaxf(mx, acc);
    }
    sc[i] = acc;
  }
  #pragma unroll
  for (int off = 32; off > 0; off >>= 1) mx = fmaxf(mx, __shfl_xor(mx, off));
  float sum = 0.f;
  #pragma unroll
  for (int i = 0; i < 4; ++i) {
    int kk = lane + i * 64;
    if (kk < nk) {
      float e = expf(sc[i] - mx);
      p_lds[kk] = e;
      sum += e;
    }
  }
  #pragma unroll
  for (int off = 32; off > 0; off >>= 1) sum += __shfl_xor(sum, off);
  __syncthreads();
  const float* Vb = QKV + rowbase + 1280 + kvh * HD_ + lane;
  float acc = 0.f;
  int kk = 0;
  for (; kk + 4 <= nk; kk += 4) {
    float4 p4 = *(const float4*)(&p_lds[kk]);  // broadcast
    acc += p4.x * Vb[(size_t)(kk + 0) * QKVN_];
    acc += p4.y * Vb[(size_t)(kk + 1) * QKVN_];
    acc += p4.z * Vb[(size_t)(kk + 2) * QKVN_];
    acc += p4.w * Vb[(size_t)(kk + 3) * QKVN_];
  }
  for (; kk < nk; ++kk) acc += p_lds[kk] * Vb[(size_t)kk * QKVN_];
  O[(size_t)(b * S_ + s) * (NH_ * HD_) + h * HD_ + lane] = __float2bfloat16(acc / sum);
}

// ---------------- silu(g)*u from packed gu -> bf16 ----------------
__global__ void silu_mul_kernel(const float* __restrict__ GU, unsigned short* __restrict__ out) {
  int idx = blockIdx.x * 256 + threadIdx.x;  // T_*256 exact
  int tok = idx >> 8, c = idx & 255;
  const float4 gv = *(const float4*)(GU + (size_t)tok * 2048 + c * 4);
  const float4 uv = *(const float4*)(GU + (size_t)tok * 2048 + 1024 + c * 4);
  ushort4 pk = { f2bf(silu_f(gv.x) * uv.x), f2bf(silu_f(gv.y) * uv.y),
                 f2bf(silu_f(gv.z) * uv.z), f2bf(silu_f(gv.w) * uv.w) };
  *(ushort4*)(out + (size_t)tok * 1024 + c * 4) = pk;
}

// ---------------- gating (fp32 VALU): logits, softmax, top-2, compact lists ----------------
__global__ void gate_kernel(const float* __restrict__ x, const float* __restrict__ gw,
                            int* __restrict__ counts, int* __restrict__ entries,
                            float* __restrict__ wgt) {
  int t = blockIdx.x;
  int lane = threadIdx.x;  // 64
  float acc[E_] = {0.f};
  const float* xr = x + (size_t)t * H_;
  for (int i = lane; i < H_; i += 64) {
    float xi = xr[i];
    const float* gr = gw + (size_t)i * E_;
    #pragma unroll
    for (int e = 0; e < E_; ++e) acc[e] = fmaf(xi, gr[e], acc[e]);
  }
  #pragma unroll
  for (int e = 0; e < E_; ++e) {
    float v = acc[e];
    #pragma unroll
    for (int off = 32; off > 0; off >>= 1) v += __shfl_xor(v, off);
    acc[e] = v;
  }
  if (lane == 0) {
    float m = acc[0];
    #pragma unroll
    for (int e = 1; e < E_; ++e) m = fmaxf(m, acc[e]);
    float p[E_];
    #pragma unroll
    for (int e = 0; e < E_; ++e) p[e] = expf(acc[e] - m);
    int i0 = 0; float b0 = p[0];
    #pragma unroll
    for (int e = 1; e < E_; ++e) if (p[e] > b0) { b0 = p[e]; i0 = e; }
    int i1 = -1; float b1 = -1.f;
    #pragma unroll
    for (int e = 0; e < E_; ++e) if (e != i0 && p[e] > b1) { b1 = p[e]; i1 = e; }
    float inv = 1.f / (b0 + b1);
    wgt[t * 2 + 0] = b0 * inv;
    wgt[t * 2 + 1] = b1 * inv;
    int pos0 = atomicAdd(&counts[i0], 1);
    entries[i0 * T_ + pos0] = t * 2 + 0;
    int pos1 = atomicAdd(&counts[i1], 1);
    entries[i1 * T_ + pos1] = t * 2 + 1;
  }
}

// ---------------- MoE FFN1 (MFMA, gathered rows, dual-B, silu*mul -> bf16) ----------------
__global__ __launch_bounds__(256)
void moe_ffn1_kernel(const bf16* __restrict__ X, const bf16* __restrict__ W1t,
                     const bf16* __restrict__ W3t,
                     const int* __restrict__ counts, const int* __restrict__ entries,
                     bf16* __restrict__ Hb) {
  const int e = blockIdx.z;
  const int n_e = counts[e];
  const int r0 = blockIdx.y * 128;
  if (r0 >= n_e) return;
  const int f0 = blockIdx.x * 128;
  __shared__ char Al[8192], B1l[8192], B3l[8192];
  __shared__ int rowent[128];
  const int t = threadIdx.x;
  if (t < 128) { int r = r0 + t; rowent[t] = (r < n_e) ? entries[e * T_ + r] : -1; }
  __syncthreads();
  const int lane = t & 63, wid = t >> 6, wr = wid >> 1, wc = wid & 1;
  const int sr = t >> 2, sc = t & 3;
  const int c0 = sc ^ ((sr >> 1) & 3);
  const int c1 = sc ^ (((sr + 64) >> 1) & 3);
  int ea = rowent[sr], eb = rowent[sr + 64];
  const bf16* gA0 = X + (size_t)(ea < 0 ? 0 : (ea >> 1)) * H_ + c0 * 8;
  const bf16* gA1 = X + (size_t)(eb < 0 ? 0 : (eb >> 1)) * H_ + c1 * 8;
  const bf16* W1b = W1t + (size_t)e * F_ * H_;  // [F][H]
  const bf16* W3b = W3t + (size_t)e * F_ * H_;
  const bf16* gB10 = W1b + (size_t)(f0 + sr) * H_ + c0 * 8;
  const bf16* gB11 = W1b + (size_t)(f0 + sr + 64) * H_ + c1 * 8;
  const bf16* gB30 = W3b + (size_t)(f0 + sr) * H_ + c0 * 8;
  const bf16* gB31 = W3b + (size_t)(f0 + sr + 64) * H_ + c1 * 8;
  char* lA0 = Al + t * 16;   char* lA1 = Al + 4096 + t * 16;
  char* l10 = B1l + t * 16;  char* l11 = B1l + 4096 + t * 16;
  char* l30 = B3l + t * 16;  char* l31 = B3l + 4096 + t * 16;
  const int la = lane & 15, kg = lane >> 4;
  const int swz = (kg ^ ((la >> 1) & 3)) * 16;
  const int aoff = (wr * 64 + la) * 64 + swz;
  const int boff = (wc * 64 + la) * 64 + swz;
  f32x4 acc1[4][4] = {}, acc3[4][4] = {};
  for (int k0 = 0; k0 < H_; k0 += 32) {
    stage16(gA0 + k0, lA0);
    stage16(gA1 + k0, lA1);
    stage16(gB10 + k0, l10);
    stage16(gB11 + k0, l11);
    stage16(gB30 + k0, l30);
    stage16(gB31 + k0, l31);
    __syncthreads();
    bf16x8 af[4], b1f[4], b3f[4];
    #pragma unroll
    for (int i = 0; i < 4; ++i) af[i] = *(const bf16x8*)(Al + aoff + i * 1024);
    #pragma unroll
    for (int i = 0; i < 4; ++i) b1f[i] = *(const bf16x8*)(B1l + boff + i * 1024);
    #pragma unroll
    for (int i = 0; i < 4; ++i) b3f[i] = *(const bf16x8*)(B3l + boff + i * 1024);
    #pragma unroll
    for (int mi = 0; mi < 4; ++mi)
      #pragma unroll
      for (int ni = 0; ni < 4; ++ni) {
        acc1[mi][ni] = __builtin_amdgcn_mfma_f32_16x16x32_bf16(af[mi], b1f[ni], acc1[mi][ni], 0, 0, 0);
        acc3[mi][ni] = __builtin_amdgcn_mfma_f32_16x16x32_bf16(af[mi], b3f[ni], acc3[mi][ni], 0, 0, 0);
      }
    __syncthreads();
  }
  #pragma unroll
  for (int mi = 0; mi < 4; ++mi) {
    int rloc = wr * 64 + mi * 16 + kg * 4;
    #pragma unroll
    for (int ni = 0; ni < 4; ++ni) {
      int col = f0 + wc * 64 + ni * 16 + la;
      #pragma unroll
      for (int r = 0; r < 4; ++r) {
        int ent = rowent[rloc + r];
        if (ent < 0) continue;
        float gv = acc1[mi][ni][r], uv = acc3[mi][ni][r];
        Hb[(size_t)ent * F_ + col] = __float2bfloat16(silu_f(gv) * uv);
      }
    }
  }
}

// ---------------- MoE FFN2 (MFMA, gathered rows) ----------------
__global__ __launch_bounds__(256)
void moe_ffn2_kernel(const bf16* __restrict__ Hb, const bf16* __restrict__ W2t,
                     const int* __restrict__ counts, const int* __restrict__ entries,
                     float* __restrict__ Y) {
  const int e = blockIdx.z;
  const int n_e = counts[e];
  const int r0 = blockIdx.y * 128;
  if (r0 >= n_e) return;
  const int n0 = blockIdx.x * 128;
  __shared__ char Al[8192], Bl[8192];
  __shared__ int rowent[128];
  const int t = threadIdx.x;
  if (t < 128) { int r = r0 + t; rowent[t] = (r < n_e) ? entries[e * T_ + r] : -1; }
  __syncthreads();
  const int lane = t & 63, wid = t >> 6, wr = wid >> 1, wc = wid & 1;
  const int sr = t >> 2, sc = t & 3;
  const int c0 = sc ^ ((sr >> 1) & 3);
  const int c1 = sc ^ (((sr + 64) >> 1) & 3);
  int ea = rowent[sr], eb = rowent[sr + 64];
  const bf16* gA0 = Hb + (size_t)(ea < 0 ? 0 : ea) * F_ + c0 * 8;
  const bf16* gA1 = Hb + (size_t)(eb < 0 ? 0 : eb) * F_ + c1 * 8;
  const bf16* W2b = W2t + (size_t)e * H_ * F_;  // [H][F]
  const bf16* gB0 = W2b + (size_t)(n0 + sr) * F_ + c0 * 8;
  const bf16* gB1 = W2b + (size_t)(n0 + sr + 64) * F_ + c1 * 8;
  char* lA0 = Al + t * 16;  char* lA1 = Al + 4096 + t * 16;
  char* lB0 = Bl + t * 16;  char* lB1 = Bl + 4096 + t * 16;
  const int la = lane & 15, kg = lane >> 4;
  const int swz = (kg ^ ((la >> 1) & 3)) * 16;
  const int aoff = (wr * 64 + la) * 64 + swz;
  const int boff = (wc * 64 + la) * 64 + swz;
  f32x4 acc[4][4] = {};
  for (int k0 = 0; k0 < F_; k0 += 32) {
    stage16(gA0 + k0, lA0);
    stage16(gA1 + k0, lA1);
    stage16(gB0 + k0, lB0);
    stage16(gB1 + k0, lB1);
    __syncthreads();
    bf16x8 af[4], bf[4];
    #pragma unroll
    for (int i = 0; i < 4; ++i) af[i] = *(const bf16x8*)(Al + aoff + i * 1024);
    #pragma unroll
    for (int i = 0; i < 4; ++i) bf[i] = *(const bf16x8*)(Bl + boff + i * 1024);
    #pragma unroll
    for (int mi = 0; mi < 4; ++mi)
      #pragma unroll
      for (int ni = 0; ni < 4; ++ni)
        acc[mi][ni] = __builtin_amdgcn_mfma_f32_16x16x32_bf16(af[mi], bf[ni], acc[mi][ni], 0, 0, 0);
    __syncthreads();
  }
  #pragma unroll
  for (int mi = 0; mi < 4; ++mi) {
    int rloc = wr * 64 + mi * 16 + kg * 4;
    #pragma unroll
    for (int ni = 0; ni < 4; ++ni) {
      int col = n0 + wc * 64 + ni * 16 + la;
      #pragma unroll
      for (int r = 0; r < 4; ++r) {
        int ent = rowent[rloc + r];
        if (ent < 0) continue;
        Y[(size_t)ent * H_ + col] = acc[mi][ni][r];
      }
    }
  }
}

// ---------------- combine: out[t] += w0*Y[2t] + w1*Y[2t+1] ----------------
__global__ void combine_kernel(const float* __restrict__ Y, const float* __restrict__ wgt,
                               float* __restrict__ out) {
  int t = blockIdx.x;
  int c = threadIdx.x;  // 256
  float w0 = wgt[t * 2], w1 = wgt[t * 2 + 1];
  float4 y0 = *(const float4*)(&Y[((size_t)t * 2) * H_ + c * 4]);
  float4 y1 = *(const float4*)(&Y[((size_t)t * 2 + 1) * H_ + c * 4]);
  float4 o  = *(float4*)(&out[(size_t)t * H_ + c * 4]);
  o.x += w0 * y0.x + w1 * y1.x;
  o.y += w0 * y0.y + w1 * y1.y;
  o.z += w0 * y0.z + w1 * y1.z;
  o.w += w0 * y0.w + w1 * y1.w;
  *(float4*)(&out[(size_t)t * H_ + c * 4]) = o;
}

extern "C" void kernel_launch(void* const* d_in, const int* in_sizes, int n_in,
                              void* d_out, int out_size, void* d_ws, size_t ws_size,
                              hipStream_t stream) {
  const float* hidden    = (const float*)d_in[0];
  const float* ln1_w     = (const float*)d_in[1];
  const float* q_w       = (const float*)d_in[2];
  const float* k_w       = (const float*)d_in[3];
  const float* v_w       = (const float*)d_in[4];
  const float* o_w       = (const float*)d_in[5];
  const float* res_ln_w  = (const float*)d_in[6];
  const float* rw1       = (const float*)d_in[7];
  const float* rw3       = (const float*)d_in[8];
  const float* rw2       = (const float*)d_in[9];
  const float* post_ln_w = (const float*)d_in[10];
  const float* gate_w    = (const float*)d_in[11];
  const float* e_w1      = (const float*)d_in[12];
  const float* e_w3      = (const float*)d_in[13];
  const float* e_w2      = (const float*)d_in[14];
  float* out = (float*)d_out;

  char* base = (char*)d_ws;
  size_t off = 0;
  auto alloc = [&](size_t bytes) -> void* {
    void* p = base + off;
    off += (bytes + 255) & ~(size_t)255;
    return p;
  };
  float* qkvf   = (float*)alloc((size_t)T_ * QKVN_ * 4);
  float* costab = (float*)alloc((size_t)S_ * 32 * 4);
  float* sintab = (float*)alloc((size_t)S_ * 32 * 4);
  float* resat  = (float*)alloc((size_t)T_ * H_ * 4);
  float* gu     = (float*)alloc((size_t)T_ * 2048 * 4);
  float* h3f    = (float*)alloc((size_t)T_ * H_ * 4);
  float* wgt    = (float*)alloc((size_t)T_ * 2 * 4);
  float* Y      = (float*)alloc((size_t)T_ * 2 * H_ * 4);
  bf16* h1b     = (bf16*)alloc((size_t)T_ * H_ * 2);
  bf16* h2b     = (bf16*)alloc((size_t)T_ * H_ * 2);
  bf16* h3b     = (bf16*)alloc((size_t)T_ * H_ * 2);
  bf16* attnb   = (bf16*)alloc((size_t)T_ * H_ * 2);
  bf16* gb      = (bf16*)alloc((size_t)T_ * H_ * 2);
  bf16* Hb      = (bf16*)alloc((size_t)T_ * 2 * F_ * 2);
  bf16* qkvwt   = (bf16*)alloc((size_t)QKVN_ * H_ * 2);
  bf16* owt     = (bf16*)alloc((size_t)H_ * H_ * 2);
  bf16* w13t    = (bf16*)alloc((size_t)2048 * H_ * 2);
  bf16* rw2t    = (bf16*)alloc((size_t)H_ * H_ * 2);
  bf16* ew1t    = (bf16*)alloc((size_t)E_ * F_ * H_ * 2);
  bf16* ew3t    = (bf16*)alloc((size_t)E_ * F_ * H_ * 2);
  bf16* ew2t    = (bf16*)alloc((size_t)E_ * H_ * F_ * 2);
  int* counts   = (int*)alloc(64);
  int* entries  = (int*)alloc((size_t)E_ * T_ * 4);

  zero_counts_kernel<<<1, 64, 0, stream>>>(counts);
  rope_table_kernel<<<(S_ * 32 + 255) / 256, 256, 0, stream>>>(costab, sintab);

  // weight prep: fp32 [K][N] -> bf16 [N][K]
  transpose_cvt_kernel<<<dim3(32, 32, 1), 256, 0, stream>>>(q_w, qkvwt, 1024, 1024);
  transpose_cvt_kernel<<<dim3(32, 8, 1), 256, 0, stream>>>(k_w, qkvwt + (size_t)1024 * 1024, 1024, 256);
  transpose_cvt_kernel<<<dim3(32, 8, 1), 256, 0, stream>>>(v_w, qkvwt + (size_t)1280 * 1024, 1024, 256);
  transpose_cvt_kernel<<<dim3(32, 32, 1), 256, 0, stream>>>(o_w, owt, 1024, 1024);
  transpose_cvt_kernel<<<dim3(32, 32, 1), 256, 0, stream>>>(rw1, w13t, 1024, 1024);
  transpose_cvt_kernel<<<dim3(32, 32, 1), 256, 0, stream>>>(rw3, w13t + (size_t)1024 * 1024, 1024, 1024);
  transpose_cvt_kernel<<<dim3(32, 32, 1), 256, 0, stream>>>(rw2, rw2t, 1024, 1024);
  transpose_cvt_kernel<<<dim3(32, 88, 8), 256, 0, stream>>>(e_w1, ew1t, 1024, 2816);
  transpose_cvt_kernel<<<dim3(32, 88, 8), 256, 0, stream>>>(e_w3, ew3t, 1024, 2816);
  transpose_cvt_kernel<<<dim3(88, 32, 8), 256, 0, stream>>>(e_w2, ew2t, 2816, 1024);

  // attention path
  rms_kernel<false><<<T_, 256, 0, stream>>>(hidden, ln1_w, h1b, nullptr);
  mm_kernel<false><<<dim3(QKVN_ / 128, T_ / 128), 256, 0, stream>>>(h1b, qkvwt, nullptr, qkvf, T_, QKVN_, H_);
  rope_apply_kernel<<<(T_ * NH_ * 32 + 255) / 256, 256, 0, stream>>>(qkvf, costab, sintab, NH_, QKVN_, T_ * NH_ * 32);
  rope_apply_kernel<<<(T_ * NKV_ * 32 + 255) / 256, 256, 0, stream>>>(qkvf + 1024, costab, sintab, NKV_, QKVN_, T_ * NKV_ * 32);
  attn_kernel<<<dim3(S_, NH_, B_), 64, 0, stream>>>(qkvf, attnb);
  mm_kernel<true><<<dim3(8, 16), 256, 0, stream>>>(attnb, owt, hidden, resat, T_, H_, H_);

  // parallel residual dense MLP
  rms_kernel<false><<<T_, 256, 0, stream>>>(resat, res_ln_w, h2b, nullptr);
  mm_kernel<false><<<dim3(16, 16), 256, 0, stream>>>(h2b, w13t, nullptr, gu, T_, 2048, H_);
  silu_mul_kernel<<<T_, 256, 0, stream>>>(gu, (unsigned short*)gb);
  mm_kernel<true><<<dim3(8, 16), 256, 0, stream>>>(gb, rw2t, resat, out, T_, H_, H_);

  // MoE path on the ORIGINAL layer input
  rms_kernel<true><<<T_, 256, 0, stream>>>(hidden, post_ln_w, h3b, h3f);
  gate_kernel<<<T_, 64, 0, stream>>>(h3f, gate_w, counts, entries, wgt);
  moe_ffn1_kernel<<<dim3(F_ / 128, 16, E_), 256, 0, stream>>>(h3b, ew1t, ew3t, counts, entries, Hb);
  moe_ffn2_kernel<<<dim3(8, 16, E_), 256, 0, stream>>>(Hb, ew2t, counts, entries, Y);
  combine_kernel<<<T_, 256, 0, stream>>>(Y, wgt, out);
}

// Round 6
// 775.171 us; speedup vs baseline: 1.3763x; 1.3763x over previous
//
#include <hip/hip_runtime.h>
#include <hip/hip_bf16.h>
#include <math.h>

// Problem constants (Arctic decoder layer)
#define B_    2
#define S_    1024
#define H_    1024
#define NH_   16
#define NKV_  4
#define HD_   64
#define F_    2816
#define E_    8
#define WIN_  256
#define T_    (B_*S_)
#define EPS_  1e-5f
#define QKVN_ 1536

typedef __hip_bfloat16 bf16;
using f32x4  = __attribute__((ext_vector_type(4))) float;
using bf16x8 = __attribute__((ext_vector_type(8))) short;

__device__ __forceinline__ float silu_f(float x) { return x / (1.0f + expf(-x)); }

__device__ __forceinline__ unsigned short f2bf(float v) {
  __hip_bfloat16 b = __float2bfloat16(v);
  return *reinterpret_cast<unsigned short*>(&b);
}

// async global->LDS 16B stage (linear LDS dst: wave-uniform base + lane*16)
__device__ __forceinline__ void stage16(const void* g, void* l) {
#if defined(__has_builtin) && __has_builtin(__builtin_amdgcn_global_load_lds)
  __builtin_amdgcn_global_load_lds((const __attribute__((address_space(1))) unsigned int*)g,
                                   (__attribute__((address_space(3))) unsigned int*)l,
                                   16, 0, 0);
#else
  *(float4*)l = *(const float4*)g;
#endif
}

// ---------------- RoPE tables (+ zero MoE counters, fused) ----------------
__global__ void rope_table_kernel(float* __restrict__ costab, float* __restrict__ sintab,
                                  int* __restrict__ counts) {
  int idx = blockIdx.x * blockDim.x + threadIdx.x;  // S_*32
  if (blockIdx.x == 0 && threadIdx.x < E_) counts[threadIdx.x] = 0;
  if (idx >= S_ * 32) return;
  int s = idx >> 5, j = idx & 31;
  float inv = powf(10000.0f, -(float)j / 32.0f);
  float ang = (float)s * inv;
  costab[idx] = cosf(ang);
  sintab[idx] = sinf(ang);
}

// ---------------- transpose + fp32->bf16: src[K][N] -> dst[N][K] ----------------
// variant A: z = batch index into ONE array (expert weights)
__global__ void transpose_cvt_kernel(const float* __restrict__ src, bf16* __restrict__ dst,
                                     int K, int N) {
  __shared__ float tile[32][33];
  const size_t bstride = (size_t)K * N;
  src += bstride * blockIdx.z;
  dst += bstride * blockIdx.z;
  int bk = blockIdx.x * 32, bn = blockIdx.y * 32;
  int tx = threadIdx.x & 31, ty = threadIdx.x >> 5;  // 256 thr: ty 0..7
  #pragma unroll
  for (int i = 0; i < 4; ++i)
    tile[ty + i * 8][tx] = src[(size_t)(bk + ty + i * 8) * N + bn + tx];
  __syncthreads();
  #pragma unroll
  for (int i = 0; i < 4; ++i)
    dst[(size_t)(bn + ty + i * 8) * K + bk + tx] = __float2bfloat16(tile[tx][ty + i * 8]);
}

// variant B: z selects (src,dst) pair from a pointer batch (distinct weights, one launch)
struct TransBatch { const float* src[5]; bf16* dst[5]; };
__global__ void transpose_cvt5_kernel(TransBatch tb, int K, int N) {
  __shared__ float tile[32][33];
  const float* src = tb.src[blockIdx.z];
  bf16* dst = tb.dst[blockIdx.z];
  int bk = blockIdx.x * 32, bn = blockIdx.y * 32;
  int tx = threadIdx.x & 31, ty = threadIdx.x >> 5;
  #pragma unroll
  for (int i = 0; i < 4; ++i)
    tile[ty + i * 8][tx] = src[(size_t)(bk + ty + i * 8) * N + bn + tx];
  __syncthreads();
  #pragma unroll
  for (int i = 0; i < 4; ++i)
    dst[(size_t)(bn + ty + i * 8) * K + bk + tx] = __float2bfloat16(tile[tx][ty + i * 8]);
}

// ---------------- RMSNorm: fp32 in -> bf16 out ----------------
__global__ void rms_kernel(const float* __restrict__ x, const float* __restrict__ w,
                           bf16* __restrict__ ob) {
  const int row = blockIdx.x, t = threadIdx.x;  // 256
  const float* xr = x + (size_t)row * H_;
  float4 v = *(const float4*)(&xr[t * 4]);
  float ss = v.x*v.x + v.y*v.y + v.z*v.z + v.w*v.w;
  #pragma unroll
  for (int o = 32; o > 0; o >>= 1) ss += __shfl_xor(ss, o);
  __shared__ float red[4];
  if ((t & 63) == 0) red[t >> 6] = ss;
  __syncthreads();
  float tot = red[0] + red[1] + red[2] + red[3];
  float scale = rsqrtf(tot * (1.0f / H_) + EPS_);
  float4 wv = *(const float4*)(&w[t * 4]);
  ushort4 pk = { f2bf(v.x*scale*wv.x), f2bf(v.y*scale*wv.y),
                 f2bf(v.z*scale*wv.z), f2bf(v.w*scale*wv.w) };
  *(ushort4*)((unsigned short*)ob + (size_t)row * H_ + t * 4) = pk;
}

// ---------------- fused RMSNorm + MoE gate (fp32 logits, top-2, compact lists) ----------------
__global__ void rms_gate_kernel(const float* __restrict__ x, const float* __restrict__ w,
                                const float* __restrict__ gw, bf16* __restrict__ ob,
                                int* __restrict__ counts, int* __restrict__ entries,
                                float* __restrict__ wgt) {
  const int row = blockIdx.x, t = threadIdx.x;  // 256
  const float* xr = x + (size_t)row * H_;
  float4 v = *(const float4*)(&xr[t * 4]);
  float ss = v.x*v.x + v.y*v.y + v.z*v.z + v.w*v.w;
  #pragma unroll
  for (int o = 32; o > 0; o >>= 1) ss += __shfl_xor(ss, o);
  __shared__ float red[4];
  __shared__ float sm[4][8];
  if ((t & 63) == 0) red[t >> 6] = ss;
  __syncthreads();
  float tot = red[0] + red[1] + red[2] + red[3];
  float scale = rsqrtf(tot * (1.0f / H_) + EPS_);
  float4 wv = *(const float4*)(&w[t * 4]);
  float o0 = v.x*scale*wv.x, o1 = v.y*scale*wv.y, o2 = v.z*scale*wv.z, o3 = v.w*scale*wv.w;
  ushort4 pk = { f2bf(o0), f2bf(o1), f2bf(o2), f2bf(o3) };
  *(ushort4*)((unsigned short*)ob + (size_t)row * H_ + t * 4) = pk;
  // gate logits: this thread's 4 columns (t*4..t*4+3), gw is [H][E] row-major
  const float* gr = gw + (size_t)(t * 4) * E_;
  float acc[E_];
  #pragma unroll
  for (int e = 0; e < E_; ++e)
    acc[e] = o0 * gr[e] + o1 * gr[E_ + e] + o2 * gr[2 * E_ + e] + o3 * gr[3 * E_ + e];
  #pragma unroll
  for (int e = 0; e < E_; ++e) {
    #pragma unroll
    for (int o = 32; o > 0; o >>= 1) acc[e] += __shfl_xor(acc[e], o);
  }
  if ((t & 63) == 0) {
    #pragma unroll
    for (int e = 0; e < E_; ++e) sm[t >> 6][e] = acc[e];
  }
  __syncthreads();
  if (t == 0) {
    float lg[E_];
    #pragma unroll
    for (int e = 0; e < E_; ++e) lg[e] = sm[0][e] + sm[1][e] + sm[2][e] + sm[3][e];
    float m = lg[0];
    #pragma unroll
    for (int e = 1; e < E_; ++e) m = fmaxf(m, lg[e]);
    float p[E_];
    #pragma unroll
    for (int e = 0; e < E_; ++e) p[e] = expf(lg[e] - m);
    int i0 = 0; float b0 = p[0];
    #pragma unroll
    for (int e = 1; e < E_; ++e) if (p[e] > b0) { b0 = p[e]; i0 = e; }
    int i1 = -1; float b1 = -1.f;
    #pragma unroll
    for (int e = 0; e < E_; ++e) if (e != i0 && p[e] > b1) { b1 = p[e]; i1 = e; }
    float inv = 1.f / (b0 + b1);
    wgt[row * 2 + 0] = b0 * inv;
    wgt[row * 2 + 1] = b1 * inv;
    int pos0 = atomicAdd(&counts[i0], 1);
    entries[i0 * T_ + pos0] = row * 2 + 0;
    int pos1 = atomicAdd(&counts[i1], 1);
    entries[i1 * T_ + pos1] = row * 2 + 1;
  }
}

// =====================================================================
// bf16 MFMA GEMM: C[M,N] = A[M,K](bf16) @ Bt[N,K](bf16)^T (+Res), fp32 out
// 128xBN tile (BN=128 or 64), BK=32, 256 thr (4 waves), m97 structure.
// =====================================================================
template <int BN, bool ADD_RES>
__global__ __launch_bounds__(256)
void mm_kernel(const bf16* __restrict__ A, const bf16* __restrict__ Bt,
               const float* __restrict__ Res, float* __restrict__ C,
               int M, int N, int K) {
  __shared__ char Al[8192];
  __shared__ char Bl[BN * 64];
  const int t = threadIdx.x;
  const int m0 = blockIdx.y * 128, n0 = blockIdx.x * BN;
  const int lane = t & 63, wid = t >> 6;
  const int wr = wid >> 1, wc = wid & 1;
  const int sr = t >> 2, sc = t & 3;
  const int cA0 = sc ^ ((sr >> 1) & 3);
  const int cA1 = sc ^ (((sr + 64) >> 1) & 3);
  const bf16* gA0 = A + (size_t)(m0 + sr) * K + cA0 * 8;
  const bf16* gA1 = A + (size_t)(m0 + sr + 64) * K + cA1 * 8;
  const bf16* gB0 = Bt + (size_t)(n0 + sr) * K + cA0 * 8;
  const bf16* gB1 = Bt + (size_t)(n0 + sr + 64) * K + cA1 * 8;  // unused if BN==64
  char* lA0 = Al + t * 16;
  char* lA1 = Al + 4096 + t * 16;
  char* lB0 = Bl + t * 16;
  char* lB1 = Bl + 4096 + t * 16;
  const int la = lane & 15, kg = lane >> 4;
  const int swz = (kg ^ ((la >> 1) & 3)) * 16;
  const int aoff = (wr * 64 + la) * 64 + swz;
  constexpr int NW = BN / 32;          // frags per wave in N (4 or 2)
  const int boff = (wc * (BN / 2) + la) * 64 + swz;
  f32x4 acc[4][NW] = {};
  for (int k0 = 0; k0 < K; k0 += 32) {
    stage16(gA0 + k0, lA0);
    stage16(gA1 + k0, lA1);
    stage16(gB0 + k0, lB0);
    if constexpr (BN == 128) stage16(gB1 + k0, lB1);
    __syncthreads();
    bf16x8 af[4], bfr[NW];
    #pragma unroll
    for (int i = 0; i < 4; ++i) af[i] = *(const bf16x8*)(Al + aoff + i * 1024);
    #pragma unroll
    for (int i = 0; i < NW; ++i) bfr[i] = *(const bf16x8*)(Bl + boff + i * 1024);
    #pragma unroll
    for (int mi = 0; mi < 4; ++mi)
      #pragma unroll
      for (int ni = 0; ni < NW; ++ni)
        acc[mi][ni] = __builtin_amdgcn_mfma_f32_16x16x32_bf16(af[mi], bfr[ni], acc[mi][ni], 0, 0, 0);
    __syncthreads();
  }
  #pragma unroll
  for (int mi = 0; mi < 4; ++mi) {
    int row = m0 + wr * 64 + mi * 16 + kg * 4;
    #pragma unroll
    for (int ni = 0; ni < NW; ++ni) {
      int col = n0 + wc * (BN / 2) + ni * 16 + la;
      #pragma unroll
      for (int r = 0; r < 4; ++r) {
        size_t off = (size_t)(row + r) * N + col;
        float v = acc[mi][ni][r];
        if (ADD_RES) v += Res[off];
        C[off] = v;
      }
    }
  }
}

// ---------------- RoPE + cvt, merged Q and K (head 0..19) ----------------
__global__ void rope_cvt_qk_kernel(const float* __restrict__ QKV, const float* __restrict__ ct,
                                   const float* __restrict__ st, bf16* __restrict__ Qb,
                                   bf16* __restrict__ Kb) {
  int idx = blockIdx.x * 256 + threadIdx.x;  // T_*20*32
  int j = idx & 31;
  int hh = (idx >> 5) % 20;
  int t = idx / (32 * 20);
  int s = t & (S_ - 1), b = t >> 10;
  float c = ct[s * 32 + j], sn = st[s * 32 + j];
  if (hh < NH_) {
    const float* src = QKV + (size_t)t * QKVN_ + hh * HD_;
    float x1 = src[j], x2 = src[j + 32];
    bf16* dst = Qb + ((size_t)(b * NH_ + hh) * S_ + s) * HD_;
    dst[j]      = __float2bfloat16((x1 * c - x2 * sn) * 0.125f);
    dst[j + 32] = __float2bfloat16((x2 * c + x1 * sn) * 0.125f);
  } else {
    int kvh = hh - NH_;
    const float* src = QKV + (size_t)t * QKVN_ + 1024 + kvh * HD_;
    float x1 = src[j], x2 = src[j + 32];
    bf16* dst = Kb + ((size_t)(b * NKV_ + kvh) * S_ + s) * HD_;
    dst[j]      = __float2bfloat16(x1 * c - x2 * sn);
    dst[j + 32] = __float2bfloat16(x2 * c + x1 * sn);
  }
}

// ---------------- V transpose: qkvf V section -> Vt[b][kvh][d][s] bf16 ----------------
__global__ void vt_kernel(const float* __restrict__ QKV, bf16* __restrict__ Vt) {
  int p = blockIdx.z;  // b*NKV+kvh
  int b = p >> 2, kvh = p & 3;
  int s0 = blockIdx.x * 32, d0 = blockIdx.y * 32;
  __shared__ float tile[32][33];
  int tx = threadIdx.x & 31, ty = threadIdx.x >> 5;
  const float* src = QKV + (size_t)(b * S_) * QKVN_ + 1280 + kvh * HD_;
  #pragma unroll
  for (int i = 0; i < 4; ++i)
    tile[ty + i * 8][tx] = src[(size_t)(s0 + ty + i * 8) * QKVN_ + d0 + tx];
  __syncthreads();
  bf16* dst = Vt + (size_t)p * HD_ * S_;
  #pragma unroll
  for (int i = 0; i < 4; ++i)
    dst[(size_t)(d0 + ty + i * 8) * S_ + s0 + tx] = __float2bfloat16(tile[tx][ty + i * 8]);
}

// =====================================================================
// MFMA flash attention, sliding window. 1 wave = 16 queries of one (b,h).
// Swapped operands: S^T = mfma(K, Q) -> lane's regs all belong to query
// col = lane&15  ->  per-lane scalar softmax state. No LDS, no barriers.
// =====================================================================
__global__ __launch_bounds__(256)
void attn_kernel(const bf16* __restrict__ Qb, const bf16* __restrict__ Kb,
                 const bf16* __restrict__ Vt, bf16* __restrict__ O) {
  const int w = threadIdx.x >> 6, lane = threadIdx.x & 63;
  const int qw = blockIdx.x * 64 + w * 16;
  const int h = blockIdx.y, b = blockIdx.z, kvh = h >> 2;
  const int g = lane >> 4, qcol = lane & 15;
  const bf16* Qp = Qb + ((size_t)(b * NH_ + h) * S_ + qw) * HD_;
  const bf16* Kp = Kb + (size_t)(b * NKV_ + kvh) * S_ * HD_;
  const bf16* Vp = Vt + (size_t)(b * NKV_ + kvh) * HD_ * S_;
  const bf16x8 qf0 = *(const bf16x8*)(Qp + qcol * HD_ + g * 8);
  const bf16x8 qf1 = *(const bf16x8*)(Qp + qcol * HD_ + 32 + g * 8);
  const int q = qw + qcol;
  float m = -3.0e38f, lsum = 0.f;
  f32x4 o[4] = {};
  int kstart = qw - (WIN_ - 1); if (kstart < 0) kstart = 0; kstart &= ~31;
  const int kend = qw + 16;  // exclusive; last tile base <= S_-32, no OOB
  for (int kt = kstart; kt < kend; kt += 32) {
    f32x4 s0 = {}, s1 = {};
    {
      const bf16* kr0 = Kp + (size_t)(kt + qcol) * HD_ + g * 8;
      const bf16* kr1 = kr0 + 16 * HD_;
      bf16x8 kf;
      kf = *(const bf16x8*)(kr0);      s0 = __builtin_amdgcn_mfma_f32_16x16x32_bf16(kf, qf0, s0, 0, 0, 0);
      kf = *(const bf16x8*)(kr0 + 32); s0 = __builtin_amdgcn_mfma_f32_16x16x32_bf16(kf, qf1, s0, 0, 0, 0);
      kf = *(const bf16x8*)(kr1);      s1 = __builtin_amdgcn_mfma_f32_16x16x32_bf16(kf, qf0, s1, 0, 0, 0);
      kf = *(const bf16x8*)(kr1 + 32); s1 = __builtin_amdgcn_mfma_f32_16x16x32_bf16(kf, qf1, s1, 0, 0, 0);
    }
    bool v0[4], v1[4];
    float pmax = -3.0e38f;
    #pragma unroll
    for (int r = 0; r < 4; ++r) {
      int k0r = kt + 4 * g + r;
      int k1r = k0r + 16;
      v0[r] = (k0r <= q) && (q - k0r < WIN_);
      v1[r] = (k1r <= q) && (q - k1r < WIN_);
      s0[r] = v0[r] ? s0[r] : -3.0e38f;
      s1[r] = v1[r] ? s1[r] : -3.0e38f;
      pmax = fmaxf(pmax, fmaxf(s0[r], s1[r]));
    }
    pmax = fmaxf(pmax, __shfl_xor(pmax, 16));
    pmax = fmaxf(pmax, __shfl_xor(pmax, 32));
    const float mnew = fmaxf(m, pmax);
    const float scale = __expf(m - mnew);
    float p0[4], p1[4], psum = 0.f;
    #pragma unroll
    for (int r = 0; r < 4; ++r) {
      p0[r] = v0[r] ? __expf(s0[r] - mnew) : 0.f;  // explicit 0: mnew may be -3e38
      p1[r] = v1[r] ? __expf(s1[r] - mnew) : 0.f;
      psum += p0[r] + p1[r];
    }
    lsum = lsum * scale + psum;
    #pragma unroll
    for (int df = 0; df < 4; ++df) {
      o[df][0] *= scale; o[df][1] *= scale; o[df][2] *= scale; o[df][3] *= scale;
    }
    m = mnew;
    // redistribute P^T into PV B-operand: lane needs keys g*8..g*8+7 of ITS query
    unsigned pk[4];
    #pragma unroll
    for (int r = 0; r < 4; ++r) pk[r] = (unsigned)f2bf(p0[r]) | ((unsigned)f2bf(p1[r]) << 16);
    const int srcLo = ((g & 1) << 1) * 16 + qcol;
    unsigned lo[4], hi[4];
    #pragma unroll
    for (int r = 0; r < 4; ++r) {
      lo[r] = (unsigned)__shfl((int)pk[r], srcLo);
      hi[r] = (unsigned)__shfl((int)pk[r], srcLo + 16);
    }
    const bool useHi = (g >= 2);
    union { unsigned u[4]; bf16x8 v; } bp;
    {
      unsigned e0 = useHi ? (lo[0] >> 16) : (lo[0] & 0xffffu);
      unsigned e1 = useHi ? (lo[1] >> 16) : (lo[1] & 0xffffu);
      unsigned e2 = useHi ? (lo[2] >> 16) : (lo[2] & 0xffffu);
      unsigned e3 = useHi ? (lo[3] >> 16) : (lo[3] & 0xffffu);
      unsigned e4 = useHi ? (hi[0] >> 16) : (hi[0] & 0xffffu);
      unsigned e5 = useHi ? (hi[1] >> 16) : (hi[1] & 0xffffu);
      unsigned e6 = useHi ? (hi[2] >> 16) : (hi[2] & 0xffffu);
      unsigned e7 = useHi ? (hi[3] >> 16) : (hi[3] & 0xffffu);
      bp.u[0] = e0 | (e1 << 16);
      bp.u[1] = e2 | (e3 << 16);
      bp.u[2] = e4 | (e5 << 16);
      bp.u[3] = e6 | (e7 << 16);
    }
    // PV: O^T[d][q] += V^T[d][k] * P^T[k][q]
    #pragma unroll
    for (int df = 0; df < 4; ++df) {
      bf16x8 vf = *(const bf16x8*)(Vp + (size_t)(16 * df + qcol) * S_ + kt + g * 8);
      o[df] = __builtin_amdgcn_mfma_f32_16x16x32_bf16(vf, bp.v, o[df], 0, 0, 0);
    }
  }
  lsum += __shfl_xor(lsum, 16);
  lsum += __shfl_xor(lsum, 32);
  const float inv = 1.f / lsum;
  bf16* Op = O + (size_t)(b * S_ + q) * (NH_ * HD_) + h * HD_;
  #pragma unroll
  for (int df = 0; df < 4; ++df) {
    ushort4 st = { f2bf(o[df][0] * inv), f2bf(o[df][1] * inv),
                   f2bf(o[df][2] * inv), f2bf(o[df][3] * inv) };
    *(ushort4*)((unsigned short*)Op + 16 * df + 4 * g) = st;
  }
}

// ---------------- silu(g)*u from packed gu -> bf16 ----------------
__global__ void silu_mul_kernel(const float* __restrict__ GU, unsigned short* __restrict__ out) {
  int idx = blockIdx.x * 256 + threadIdx.x;  // T_*256 exact
  int tok = idx >> 8, c = idx & 255;
  const float4 gv = *(const float4*)(GU + (size_t)tok * 2048 + c * 4);
  const float4 uv = *(const float4*)(GU + (size_t)tok * 2048 + 1024 + c * 4);
  ushort4 pk = { f2bf(silu_f(gv.x) * uv.x), f2bf(silu_f(gv.y) * uv.y),
                 f2bf(silu_f(gv.z) * uv.z), f2bf(silu_f(gv.w) * uv.w) };
  *(ushort4*)(out + (size_t)tok * 1024 + c * 4) = pk;
}

// ---------------- MoE FFN1 (MFMA, gathered rows, dual-B, silu*mul -> bf16) ----------------
__global__ __launch_bounds__(256)
void moe_ffn1_kernel(const bf16* __restrict__ X, const bf16* __restrict__ W1t,
                     const bf16* __restrict__ W3t,
                     const int* __restrict__ counts, const int* __restrict__ entries,
                     bf16* __restrict__ Hb) {
  const int e = blockIdx.z;
  const int n_e = counts[e];
  const int r0 = blockIdx.y * 128;
  if (r0 >= n_e) return;
  const int f0 = blockIdx.x * 128;
  __shared__ char Al[8192], B1l[8192], B3l[8192];
  __shared__ int rowent[128];
  const int t = threadIdx.x;
  if (t < 128) { int r = r0 + t; rowent[t] = (r < n_e) ? entries[e * T_ + r] : -1; }
  __syncthreads();
  const int lane = t & 63, wid = t >> 6, wr = wid >> 1, wc = wid & 1;
  const int sr = t >> 2, sc = t & 3;
  const int c0 = sc ^ ((sr >> 1) & 3);
  const int c1 = sc ^ (((sr + 64) >> 1) & 3);
  int ea = rowent[sr], eb = rowent[sr + 64];
  const bf16* gA0 = X + (size_t)(ea < 0 ? 0 : (ea >> 1)) * H_ + c0 * 8;
  const bf16* gA1 = X + (size_t)(eb < 0 ? 0 : (eb >> 1)) * H_ + c1 * 8;
  const bf16* W1b = W1t + (size_t)e * F_ * H_;  // [F][H]
  const bf16* W3b = W3t + (size_t)e * F_ * H_;
  const bf16* gB10 = W1b + (size_t)(f0 + sr) * H_ + c0 * 8;
  const bf16* gB11 = W1b + (size_t)(f0 + sr + 64) * H_ + c1 * 8;
  const bf16* gB30 = W3b + (size_t)(f0 + sr) * H_ + c0 * 8;
  const bf16* gB31 = W3b + (size_t)(f0 + sr + 64) * H_ + c1 * 8;
  char* lA0 = Al + t * 16;   char* lA1 = Al + 4096 + t * 16;
  char* l10 = B1l + t * 16;  char* l11 = B1l + 4096 + t * 16;
  char* l30 = B3l + t * 16;  char* l31 = B3l + 4096 + t * 16;
  const int la = lane & 15, kg = lane >> 4;
  const int swz = (kg ^ ((la >> 1) & 3)) * 16;
  const int aoff = (wr * 64 + la) * 64 + swz;
  const int boff = (wc * 64 + la) * 64 + swz;
  f32x4 acc1[4][4] = {}, acc3[4][4] = {};
  for (int k0 = 0; k0 < H_; k0 += 32) {
    stage16(gA0 + k0, lA0);
    stage16(gA1 + k0, lA1);
    stage16(gB10 + k0, l10);
    stage16(gB11 + k0, l11);
    stage16(gB30 + k0, l30);
    stage16(gB31 + k0, l31);
    __syncthreads();
    bf16x8 af[4], b1f[4], b3f[4];
    #pragma unroll
    for (int i = 0; i < 4; ++i) af[i] = *(const bf16x8*)(Al + aoff + i * 1024);
    #pragma unroll
    for (int i = 0; i < 4; ++i) b1f[i] = *(const bf16x8*)(B1l + boff + i * 1024);
    #pragma unroll
    for (int i = 0; i < 4; ++i) b3f[i] = *(const bf16x8*)(B3l + boff + i * 1024);
    #pragma unroll
    for (int mi = 0; mi < 4; ++mi)
      #pragma unroll
      for (int ni = 0; ni < 4; ++ni) {
        acc1[mi][ni] = __builtin_amdgcn_mfma_f32_16x16x32_bf16(af[mi], b1f[ni], acc1[mi][ni], 0, 0, 0);
        acc3[mi][ni] = __builtin_amdgcn_mfma_f32_16x16x32_bf16(af[mi], b3f[ni], acc3[mi][ni], 0, 0, 0);
      }
    __syncthreads();
  }
  #pragma unroll
  for (int mi = 0; mi < 4; ++mi) {
    int rloc = wr * 64 + mi * 16 + kg * 4;
    #pragma unroll
    for (int ni = 0; ni < 4; ++ni) {
      int col = f0 + wc * 64 + ni * 16 + la;
      #pragma unroll
      for (int r = 0; r < 4; ++r) {
        int ent = rowent[rloc + r];
        if (ent < 0) continue;
        float gv = acc1[mi][ni][r], uv = acc3[mi][ni][r];
        Hb[(size_t)ent * F_ + col] = __float2bfloat16(silu_f(gv) * uv);
      }
    }
  }
}

// ---------------- MoE FFN2 (MFMA, gathered rows) ----------------
__global__ __launch_bounds__(256)
void moe_ffn2_kernel(const bf16* __restrict__ Hb, const bf16* __restrict__ W2t,
                     const int* __restrict__ counts, const int* __restrict__ entries,
                     float* __restrict__ Y) {
  const int e = blockIdx.z;
  const int n_e = counts[e];
  const int r0 = blockIdx.y * 128;
  if (r0 >= n_e) return;
  const int n0 = blockIdx.x * 128;
  __shared__ char Al[8192], Bl[8192];
  __shared__ int rowent[128];
  const int t = threadIdx.x;
  if (t < 128) { int r = r0 + t; rowent[t] = (r < n_e) ? entries[e * T_ + r] : -1; }
  __syncthreads();
  const int lane = t & 63, wid = t >> 6, wr = wid >> 1, wc = wid & 1;
  const int sr = t >> 2, sc = t & 3;
  const int c0 = sc ^ ((sr >> 1) & 3);
  const int c1 = sc ^ (((sr + 64) >> 1) & 3);
  int ea = rowent[sr], eb = rowent[sr + 64];
  const bf16* gA0 = Hb + (size_t)(ea < 0 ? 0 : ea) * F_ + c0 * 8;
  const bf16* gA1 = Hb + (size_t)(eb < 0 ? 0 : eb) * F_ + c1 * 8;
  const bf16* W2b = W2t + (size_t)e * H_ * F_;  // [H][F]
  const bf16* gB0 = W2b + (size_t)(n0 + sr) * F_ + c0 * 8;
  const bf16* gB1 = W2b + (size_t)(n0 + sr + 64) * F_ + c1 * 8;
  char* lA0 = Al + t * 16;  char* lA1 = Al + 4096 + t * 16;
  char* lB0 = Bl + t * 16;  char* lB1 = Bl + 4096 + t * 16;
  const int la = lane & 15, kg = lane >> 4;
  const int swz = (kg ^ ((la >> 1) & 3)) * 16;
  const int aoff = (wr * 64 + la) * 64 + swz;
  const int boff = (wc * 64 + la) * 64 + swz;
  f32x4 acc[4][4] = {};
  for (int k0 = 0; k0 < F_; k0 += 32) {
    stage16(gA0 + k0, lA0);
    stage16(gA1 + k0, lA1);
    stage16(gB0 + k0, lB0);
    stage16(gB1 + k0, lB1);
    __syncthreads();
    bf16x8 af[4], bfr[4];
    #pragma unroll
    for (int i = 0; i < 4; ++i) af[i] = *(const bf16x8*)(Al + aoff + i * 1024);
    #pragma unroll
    for (int i = 0; i < 4; ++i) bfr[i] = *(const bf16x8*)(Bl + boff + i * 1024);
    #pragma unroll
    for (int mi = 0; mi < 4; ++mi)
      #pragma unroll
      for (int ni = 0; ni < 4; ++ni)
        acc[mi][ni] = __builtin_amdgcn_mfma_f32_16x16x32_bf16(af[mi], bfr[ni], acc[mi][ni], 0, 0, 0);
    __syncthreads();
  }
  #pragma unroll
  for (int mi = 0; mi < 4; ++mi) {
    int rloc = wr * 64 + mi * 16 + kg * 4;
    #pragma unroll
    for (int ni = 0; ni < 4; ++ni) {
      int col = n0 + wc * 64 + ni * 16 + la;
      #pragma unroll
      for (int r = 0; r < 4; ++r) {
        int ent = rowent[rloc + r];
        if (ent < 0) continue;
        Y[(size_t)ent * H_ + col] = acc[mi][ni][r];
      }
    }
  }
}

// ---------------- combine: out[t] += w0*Y[2t] + w1*Y[2t+1] ----------------
__global__ void combine_kernel(const float* __restrict__ Y, const float* __restrict__ wgt,
                               float* __restrict__ out) {
  int t = blockIdx.x;
  int c = threadIdx.x;  // 256
  float w0 = wgt[t * 2], w1 = wgt[t * 2 + 1];
  float4 y0 = *(const float4*)(&Y[((size_t)t * 2) * H_ + c * 4]);
  float4 y1 = *(const float4*)(&Y[((size_t)t * 2 + 1) * H_ + c * 4]);
  float4 o  = *(float4*)(&out[(size_t)t * H_ + c * 4]);
  o.x += w0 * y0.x + w1 * y1.x;
  o.y += w0 * y0.y + w1 * y1.y;
  o.z += w0 * y0.z + w1 * y1.z;
  o.w += w0 * y0.w + w1 * y1.w;
  *(float4*)(&out[(size_t)t * H_ + c * 4]) = o;
}

extern "C" void kernel_launch(void* const* d_in, const int* in_sizes, int n_in,
                              void* d_out, int out_size, void* d_ws, size_t ws_size,
                              hipStream_t stream) {
  const float* hidden    = (const float*)d_in[0];
  const float* ln1_w     = (const float*)d_in[1];
  const float* q_w       = (const float*)d_in[2];
  const float* k_w       = (const float*)d_in[3];
  const float* v_w       = (const float*)d_in[4];
  const float* o_w       = (const float*)d_in[5];
  const float* res_ln_w  = (const float*)d_in[6];
  const float* rw1       = (const float*)d_in[7];
  const float* rw3       = (const float*)d_in[8];
  const float* rw2       = (const float*)d_in[9];
  const float* post_ln_w = (const float*)d_in[10];
  const float* gate_w    = (const float*)d_in[11];
  const float* e_w1      = (const float*)d_in[12];
  const float* e_w3      = (const float*)d_in[13];
  const float* e_w2      = (const float*)d_in[14];
  float* out = (float*)d_out;

  char* base = (char*)d_ws;
  size_t off = 0;
  auto alloc = [&](size_t bytes) -> void* {
    void* p = base + off;
    off += (bytes + 255) & ~(size_t)255;
    return p;
  };
  float* qkvf   = (float*)alloc((size_t)T_ * QKVN_ * 4);
  float* costab = (float*)alloc((size_t)S_ * 32 * 4);
  float* sintab = (float*)alloc((size_t)S_ * 32 * 4);
  float* resat  = (float*)alloc((size_t)T_ * H_ * 4);
  float* gu     = (float*)alloc((size_t)T_ * 2048 * 4);
  float* wgt    = (float*)alloc((size_t)T_ * 2 * 4);
  float* Y      = (float*)alloc((size_t)T_ * 2 * H_ * 4);
  bf16* h1b     = (bf16*)alloc((size_t)T_ * H_ * 2);
  bf16* h2b     = (bf16*)alloc((size_t)T_ * H_ * 2);
  bf16* h3b     = (bf16*)alloc((size_t)T_ * H_ * 2);
  bf16* attnb   = (bf16*)alloc((size_t)T_ * H_ * 2);
  bf16* gb      = (bf16*)alloc((size_t)T_ * H_ * 2);
  bf16* Hb      = (bf16*)alloc((size_t)T_ * 2 * F_ * 2);
  bf16* Qbuf    = (bf16*)alloc((size_t)B_ * NH_ * S_ * HD_ * 2);
  bf16* Kbuf    = (bf16*)alloc((size_t)B_ * NKV_ * S_ * HD_ * 2);
  bf16* Vtbuf   = (bf16*)alloc((size_t)B_ * NKV_ * HD_ * S_ * 2);
  bf16* qkvwt   = (bf16*)alloc((size_t)QKVN_ * H_ * 2);
  bf16* owt     = (bf16*)alloc((size_t)H_ * H_ * 2);
  bf16* w13t    = (bf16*)alloc((size_t)2048 * H_ * 2);
  bf16* rw2t    = (bf16*)alloc((size_t)H_ * H_ * 2);
  bf16* ew1t    = (bf16*)alloc((size_t)E_ * F_ * H_ * 2);
  bf16* ew3t    = (bf16*)alloc((size_t)E_ * F_ * H_ * 2);
  bf16* ew2t    = (bf16*)alloc((size_t)E_ * H_ * F_ * 2);
  int* counts   = (int*)alloc(64);
  int* entries  = (int*)alloc((size_t)E_ * T_ * 4);

  rope_table_kernel<<<(S_ * 32 + 255) / 256, 256, 0, stream>>>(costab, sintab, counts);

  // weight prep: fp32 [K][N] -> bf16 [N][K]; five 1024x1024 in ONE launch
  {
    TransBatch tb;
    tb.src[0] = q_w;  tb.dst[0] = qkvwt;
    tb.src[1] = o_w;  tb.dst[1] = owt;
    tb.src[2] = rw1;  tb.dst[2] = w13t;
    tb.src[3] = rw3;  tb.dst[3] = w13t + (size_t)1024 * 1024;
    tb.src[4] = rw2;  tb.dst[4] = rw2t;
    transpose_cvt5_kernel<<<dim3(32, 32, 5), 256, 0, stream>>>(tb, 1024, 1024);
  }
  {
    TransBatch tb = {};
    tb.src[0] = k_w;  tb.dst[0] = qkvwt + (size_t)1024 * 1024;
    tb.src[1] = v_w;  tb.dst[1] = qkvwt + (size_t)1280 * 1024;
    transpose_cvt5_kernel<<<dim3(32, 8, 2), 256, 0, stream>>>(tb, 1024, 256);
  }
  transpose_cvt_kernel<<<dim3(32, 88, 8), 256, 0, stream>>>(e_w1, ew1t, 1024, 2816);
  transpose_cvt_kernel<<<dim3(32, 88, 8), 256, 0, stream>>>(e_w3, ew3t, 1024, 2816);
  transpose_cvt_kernel<<<dim3(88, 32, 8), 256, 0, stream>>>(e_w2, ew2t, 2816, 1024);

  // attention path
  rms_kernel<<<T_, 256, 0, stream>>>(hidden, ln1_w, h1b);
  mm_kernel<64, false><<<dim3(QKVN_ / 64, T_ / 128), 256, 0, stream>>>(h1b, qkvwt, nullptr, qkvf, T_, QKVN_, H_);
  rope_cvt_qk_kernel<<<(T_ * 20 * 32) / 256, 256, 0, stream>>>(qkvf, costab, sintab, Qbuf, Kbuf);
  vt_kernel<<<dim3(32, 2, 8), 256, 0, stream>>>(qkvf, Vtbuf);
  attn_kernel<<<dim3(S_ / 64, NH_, B_), 256, 0, stream>>>(Qbuf, Kbuf, Vtbuf, attnb);
  mm_kernel<64, true><<<dim3(16, 16), 256, 0, stream>>>(attnb, owt, hidden, resat, T_, H_, H_);

  // parallel residual dense MLP
  rms_kernel<<<T_, 256, 0, stream>>>(resat, res_ln_w, h2b);
  mm_kernel<128, false><<<dim3(16, 16), 256, 0, stream>>>(h2b, w13t, nullptr, gu, T_, 2048, H_);
  silu_mul_kernel<<<T_, 256, 0, stream>>>(gu, (unsigned short*)gb);
  mm_kernel<64, true><<<dim3(16, 16), 256, 0, stream>>>(gb, rw2t, resat, out, T_, H_, H_);

  // MoE path on the ORIGINAL layer input (fused RMS + gate)
  rms_gate_kernel<<<T_, 256, 0, stream>>>(hidden, post_ln_w, gate_w, h3b, counts, entries, wgt);
  moe_ffn1_kernel<<<dim3(F_ / 128, 16, E_), 256, 0, stream>>>(h3b, ew1t, ew3t, counts, entries, Hb);
  moe_ffn2_kernel<<<dim3(8, 16, E_), 256, 0, stream>>>(Hb, ew2t, counts, entries, Y);
  combine_kernel<<<T_, 256, 0, stream>>>(Y, wgt, out);
}

// Round 7
// 749.334 us; speedup vs baseline: 1.4238x; 1.0345x over previous
//
#include <hip/hip_runtime.h>
#include <hip/hip_bf16.h>
#include <math.h>

// Problem constants (Arctic decoder layer)
#define B_    2
#define S_    1024
#define H_    1024
#define NH_   16
#define NKV_  4
#define HD_   64
#define F_    2816
#define E_    8
#define WIN_  256
#define T_    (B_*S_)
#define EPS_  1e-5f
#define QKVN_ 1536

typedef __hip_bfloat16 bf16;
using f32x4  = __attribute__((ext_vector_type(4))) float;
using bf16x8 = __attribute__((ext_vector_type(8))) short;

__device__ __forceinline__ float silu_f(float x) { return x / (1.0f + expf(-x)); }

__device__ __forceinline__ unsigned short f2bf(float v) {
  __hip_bfloat16 b = __float2bfloat16(v);
  return *reinterpret_cast<unsigned short*>(&b);
}

// async global->LDS 16B stage (linear LDS dst: wave-uniform base + lane*16)
__device__ __forceinline__ void stage16(const void* g, void* l) {
#if defined(__has_builtin) && __has_builtin(__builtin_amdgcn_global_load_lds)
  __builtin_amdgcn_global_load_lds((const __attribute__((address_space(1))) unsigned int*)g,
                                   (__attribute__((address_space(3))) unsigned int*)l,
                                   16, 0, 0);
#else
  *(float4*)l = *(const float4*)g;
#endif
}

// ---------------- RoPE tables (+ zero MoE counters, fused) ----------------
__global__ void rope_table_kernel(float* __restrict__ costab, float* __restrict__ sintab,
                                  int* __restrict__ counts) {
  int idx = blockIdx.x * blockDim.x + threadIdx.x;  // S_*32
  if (blockIdx.x == 0 && threadIdx.x < E_) counts[threadIdx.x] = 0;
  if (idx >= S_ * 32) return;
  int s = idx >> 5, j = idx & 31;
  float inv = powf(10000.0f, -(float)j / 32.0f);
  float ang = (float)s * inv;
  costab[idx] = cosf(ang);
  sintab[idx] = sinf(ang);
}

// ---------------- transpose + fp32->bf16: src[K][N] -> dst[N][K] ----------------
__global__ void transpose_cvt_kernel(const float* __restrict__ src, bf16* __restrict__ dst,
                                     int K, int N) {
  __shared__ float tile[32][33];
  const size_t bstride = (size_t)K * N;
  src += bstride * blockIdx.z;
  dst += bstride * blockIdx.z;
  int bk = blockIdx.x * 32, bn = blockIdx.y * 32;
  int tx = threadIdx.x & 31, ty = threadIdx.x >> 5;  // 256 thr: ty 0..7
  #pragma unroll
  for (int i = 0; i < 4; ++i)
    tile[ty + i * 8][tx] = src[(size_t)(bk + ty + i * 8) * N + bn + tx];
  __syncthreads();
  #pragma unroll
  for (int i = 0; i < 4; ++i)
    dst[(size_t)(bn + ty + i * 8) * K + bk + tx] = __float2bfloat16(tile[tx][ty + i * 8]);
}

// variant B: z selects (src,dst) pair from a pointer batch (distinct weights, one launch)
struct TransBatch { const float* src[5]; bf16* dst[5]; };
__global__ void transpose_cvt5_kernel(TransBatch tb, int K, int N) {
  __shared__ float tile[32][33];
  const float* src = tb.src[blockIdx.z];
  bf16* dst = tb.dst[blockIdx.z];
  int bk = blockIdx.x * 32, bn = blockIdx.y * 32;
  int tx = threadIdx.x & 31, ty = threadIdx.x >> 5;
  #pragma unroll
  for (int i = 0; i < 4; ++i)
    tile[ty + i * 8][tx] = src[(size_t)(bk + ty + i * 8) * N + bn + tx];
  __syncthreads();
  #pragma unroll
  for (int i = 0; i < 4; ++i)
    dst[(size_t)(bn + ty + i * 8) * K + bk + tx] = __float2bfloat16(tile[tx][ty + i * 8]);
}

// ---------------- RMSNorm: fp32 in -> bf16 out ----------------
__global__ void rms_kernel(const float* __restrict__ x, const float* __restrict__ w,
                           bf16* __restrict__ ob) {
  const int row = blockIdx.x, t = threadIdx.x;  // 256
  const float* xr = x + (size_t)row * H_;
  float4 v = *(const float4*)(&xr[t * 4]);
  float ss = v.x*v.x + v.y*v.y + v.z*v.z + v.w*v.w;
  #pragma unroll
  for (int o = 32; o > 0; o >>= 1) ss += __shfl_xor(ss, o);
  __shared__ float red[4];
  if ((t & 63) == 0) red[t >> 6] = ss;
  __syncthreads();
  float tot = red[0] + red[1] + red[2] + red[3];
  float scale = rsqrtf(tot * (1.0f / H_) + EPS_);
  float4 wv = *(const float4*)(&w[t * 4]);
  ushort4 pk = { f2bf(v.x*scale*wv.x), f2bf(v.y*scale*wv.y),
                 f2bf(v.z*scale*wv.z), f2bf(v.w*scale*wv.w) };
  *(ushort4*)((unsigned short*)ob + (size_t)row * H_ + t * 4) = pk;
}

// ---------------- fused RMSNorm + MoE gate (fp32 logits, top-2, compact lists) ----------------
__global__ void rms_gate_kernel(const float* __restrict__ x, const float* __restrict__ w,
                                const float* __restrict__ gw, bf16* __restrict__ ob,
                                int* __restrict__ counts, int* __restrict__ entries,
                                float* __restrict__ wgt) {
  const int row = blockIdx.x, t = threadIdx.x;  // 256
  const float* xr = x + (size_t)row * H_;
  float4 v = *(const float4*)(&xr[t * 4]);
  float ss = v.x*v.x + v.y*v.y + v.z*v.z + v.w*v.w;
  #pragma unroll
  for (int o = 32; o > 0; o >>= 1) ss += __shfl_xor(ss, o);
  __shared__ float red[4];
  __shared__ float sm[4][8];
  if ((t & 63) == 0) red[t >> 6] = ss;
  __syncthreads();
  float tot = red[0] + red[1] + red[2] + red[3];
  float scale = rsqrtf(tot * (1.0f / H_) + EPS_);
  float4 wv = *(const float4*)(&w[t * 4]);
  float o0 = v.x*scale*wv.x, o1 = v.y*scale*wv.y, o2 = v.z*scale*wv.z, o3 = v.w*scale*wv.w;
  ushort4 pk = { f2bf(o0), f2bf(o1), f2bf(o2), f2bf(o3) };
  *(ushort4*)((unsigned short*)ob + (size_t)row * H_ + t * 4) = pk;
  const float* gr = gw + (size_t)(t * 4) * E_;
  float acc[E_];
  #pragma unroll
  for (int e = 0; e < E_; ++e)
    acc[e] = o0 * gr[e] + o1 * gr[E_ + e] + o2 * gr[2 * E_ + e] + o3 * gr[3 * E_ + e];
  #pragma unroll
  for (int e = 0; e < E_; ++e) {
    #pragma unroll
    for (int o = 32; o > 0; o >>= 1) acc[e] += __shfl_xor(acc[e], o);
  }
  if ((t & 63) == 0) {
    #pragma unroll
    for (int e = 0; e < E_; ++e) sm[t >> 6][e] = acc[e];
  }
  __syncthreads();
  if (t == 0) {
    float lg[E_];
    #pragma unroll
    for (int e = 0; e < E_; ++e) lg[e] = sm[0][e] + sm[1][e] + sm[2][e] + sm[3][e];
    float m = lg[0];
    #pragma unroll
    for (int e = 1; e < E_; ++e) m = fmaxf(m, lg[e]);
    float p[E_];
    #pragma unroll
    for (int e = 0; e < E_; ++e) p[e] = expf(lg[e] - m);
    int i0 = 0; float b0 = p[0];
    #pragma unroll
    for (int e = 1; e < E_; ++e) if (p[e] > b0) { b0 = p[e]; i0 = e; }
    int i1 = -1; float b1 = -1.f;
    #pragma unroll
    for (int e = 0; e < E_; ++e) if (e != i0 && p[e] > b1) { b1 = p[e]; i1 = e; }
    float inv = 1.f / (b0 + b1);
    wgt[row * 2 + 0] = b0 * inv;
    wgt[row * 2 + 1] = b1 * inv;
    int pos0 = atomicAdd(&counts[i0], 1);
    entries[i0 * T_ + pos0] = row * 2 + 0;
    int pos1 = atomicAdd(&counts[i1], 1);
    entries[i1 * T_ + pos1] = row * 2 + 1;
  }
}

// =====================================================================
// bf16 MFMA GEMM, 2-phase double-buffered staging (T3 minimum recipe):
// issue next K-tile's global_load_lds BEFORE computing current tile;
// single barrier per step drains a prefetch that has been in flight
// for the whole compute phase.
// =====================================================================
template <int BN, bool ADD_RES>
__global__ __launch_bounds__(256)
void mm_kernel(const bf16* __restrict__ A, const bf16* __restrict__ Bt,
               const float* __restrict__ Res, float* __restrict__ C,
               int M, int N, int K) {
  __shared__ char Al[2][8192];
  __shared__ char Bl[2][BN * 64];
  const int t = threadIdx.x;
  const int m0 = blockIdx.y * 128, n0 = blockIdx.x * BN;
  const int lane = t & 63, wid = t >> 6;
  const int wr = wid >> 1, wc = wid & 1;
  const int sr = t >> 2, sc = t & 3;
  const int cA0 = sc ^ ((sr >> 1) & 3);
  const int cA1 = sc ^ (((sr + 64) >> 1) & 3);
  const bf16* gA0 = A + (size_t)(m0 + sr) * K + cA0 * 8;
  const bf16* gA1 = A + (size_t)(m0 + sr + 64) * K + cA1 * 8;
  const bf16* gB0 = Bt + (size_t)(n0 + sr) * K + cA0 * 8;
  const bf16* gB1 = Bt + (size_t)(n0 + sr + 64) * K + cA1 * 8;  // unused if BN==64
  const int la = lane & 15, kg = lane >> 4;
  const int swz = (kg ^ ((la >> 1) & 3)) * 16;
  const int aoff = (wr * 64 + la) * 64 + swz;
  constexpr int NW = BN / 32;
  const int boff = (wc * (BN / 2) + la) * 64 + swz;
  auto STAGE = [&](int buf, int k0) {
    stage16(gA0 + k0, Al[buf] + t * 16);
    stage16(gA1 + k0, Al[buf] + 4096 + t * 16);
    stage16(gB0 + k0, Bl[buf] + t * 16);
    if constexpr (BN == 128) stage16(gB1 + k0, Bl[buf] + 4096 + t * 16);
  };
  f32x4 acc[4][NW] = {};
  STAGE(0, 0);
  __syncthreads();
  for (int k0 = 0; k0 < K; k0 += 32) {
    const int cur = (k0 >> 5) & 1;
    if (k0 + 32 < K) STAGE(cur ^ 1, k0 + 32);
    bf16x8 af[4], bfr[NW];
    #pragma unroll
    for (int i = 0; i < 4; ++i) af[i] = *(const bf16x8*)(Al[cur] + aoff + i * 1024);
    #pragma unroll
    for (int i = 0; i < NW; ++i) bfr[i] = *(const bf16x8*)(Bl[cur] + boff + i * 1024);
    #pragma unroll
    for (int mi = 0; mi < 4; ++mi)
      #pragma unroll
      for (int ni = 0; ni < NW; ++ni)
        acc[mi][ni] = __builtin_amdgcn_mfma_f32_16x16x32_bf16(af[mi], bfr[ni], acc[mi][ni], 0, 0, 0);
    __syncthreads();
  }
  #pragma unroll
  for (int mi = 0; mi < 4; ++mi) {
    int row = m0 + wr * 64 + mi * 16 + kg * 4;
    #pragma unroll
    for (int ni = 0; ni < NW; ++ni) {
      int col = n0 + wc * (BN / 2) + ni * 16 + la;
      #pragma unroll
      for (int r = 0; r < 4; ++r) {
        size_t off = (size_t)(row + r) * N + col;
        float v = acc[mi][ni][r];
        if (ADD_RES) v += Res[off];
        C[off] = v;
      }
    }
  }
}

// ---------------- RoPE + cvt, merged Q and K (head 0..19) ----------------
__global__ void rope_cvt_qk_kernel(const float* __restrict__ QKV, const float* __restrict__ ct,
                                   const float* __restrict__ st, bf16* __restrict__ Qb,
                                   bf16* __restrict__ Kb) {
  int idx = blockIdx.x * 256 + threadIdx.x;  // T_*20*32
  int j = idx & 31;
  int hh = (idx >> 5) % 20;
  int t = idx / (32 * 20);
  int s = t & (S_ - 1), b = t >> 10;
  float c = ct[s * 32 + j], sn = st[s * 32 + j];
  if (hh < NH_) {
    const float* src = QKV + (size_t)t * QKVN_ + hh * HD_;
    float x1 = src[j], x2 = src[j + 32];
    bf16* dst = Qb + ((size_t)(b * NH_ + hh) * S_ + s) * HD_;
    dst[j]      = __float2bfloat16((x1 * c - x2 * sn) * 0.125f);
    dst[j + 32] = __float2bfloat16((x2 * c + x1 * sn) * 0.125f);
  } else {
    int kvh = hh - NH_;
    const float* src = QKV + (size_t)t * QKVN_ + 1024 + kvh * HD_;
    float x1 = src[j], x2 = src[j + 32];
    bf16* dst = Kb + ((size_t)(b * NKV_ + kvh) * S_ + s) * HD_;
    dst[j]      = __float2bfloat16(x1 * c - x2 * sn);
    dst[j + 32] = __float2bfloat16(x2 * c + x1 * sn);
  }
}

// ---------------- V transpose: qkvf V section -> Vt[b][kvh][d][s] bf16 ----------------
__global__ void vt_kernel(const float* __restrict__ QKV, bf16* __restrict__ Vt) {
  int p = blockIdx.z;  // b*NKV+kvh
  int b = p >> 2, kvh = p & 3;
  int s0 = blockIdx.x * 32, d0 = blockIdx.y * 32;
  __shared__ float tile[32][33];
  int tx = threadIdx.x & 31, ty = threadIdx.x >> 5;
  const float* src = QKV + (size_t)(b * S_) * QKVN_ + 1280 + kvh * HD_;
  #pragma unroll
  for (int i = 0; i < 4; ++i)
    tile[ty + i * 8][tx] = src[(size_t)(s0 + ty + i * 8) * QKVN_ + d0 + tx];
  __syncthreads();
  bf16* dst = Vt + (size_t)p * HD_ * S_;
  #pragma unroll
  for (int i = 0; i < 4; ++i)
    dst[(size_t)(d0 + ty + i * 8) * S_ + s0 + tx] = __float2bfloat16(tile[tx][ty + i * 8]);
}

// =====================================================================
// MFMA flash attention, sliding window. 1 wave = 16 queries of one (b,h).
// =====================================================================
__global__ __launch_bounds__(256)
void attn_kernel(const bf16* __restrict__ Qb, const bf16* __restrict__ Kb,
                 const bf16* __restrict__ Vt, bf16* __restrict__ O) {
  const int w = threadIdx.x >> 6, lane = threadIdx.x & 63;
  const int qw = blockIdx.x * 64 + w * 16;
  const int h = blockIdx.y, b = blockIdx.z, kvh = h >> 2;
  const int g = lane >> 4, qcol = lane & 15;
  const bf16* Qp = Qb + ((size_t)(b * NH_ + h) * S_ + qw) * HD_;
  const bf16* Kp = Kb + (size_t)(b * NKV_ + kvh) * S_ * HD_;
  const bf16* Vp = Vt + (size_t)(b * NKV_ + kvh) * HD_ * S_;
  const bf16x8 qf0 = *(const bf16x8*)(Qp + qcol * HD_ + g * 8);
  const bf16x8 qf1 = *(const bf16x8*)(Qp + qcol * HD_ + 32 + g * 8);
  const int q = qw + qcol;
  float m = -3.0e38f, lsum = 0.f;
  f32x4 o[4] = {};
  int kstart = qw - (WIN_ - 1); if (kstart < 0) kstart = 0; kstart &= ~31;
  const int kend = qw + 16;
  for (int kt = kstart; kt < kend; kt += 32) {
    f32x4 s0 = {}, s1 = {};
    {
      const bf16* kr0 = Kp + (size_t)(kt + qcol) * HD_ + g * 8;
      const bf16* kr1 = kr0 + 16 * HD_;
      bf16x8 kf;
      kf = *(const bf16x8*)(kr0);      s0 = __builtin_amdgcn_mfma_f32_16x16x32_bf16(kf, qf0, s0, 0, 0, 0);
      kf = *(const bf16x8*)(kr0 + 32); s0 = __builtin_amdgcn_mfma_f32_16x16x32_bf16(kf, qf1, s0, 0, 0, 0);
      kf = *(const bf16x8*)(kr1);      s1 = __builtin_amdgcn_mfma_f32_16x16x32_bf16(kf, qf0, s1, 0, 0, 0);
      kf = *(const bf16x8*)(kr1 + 32); s1 = __builtin_amdgcn_mfma_f32_16x16x32_bf16(kf, qf1, s1, 0, 0, 0);
    }
    bool v0[4], v1[4];
    float pmax = -3.0e38f;
    #pragma unroll
    for (int r = 0; r < 4; ++r) {
      int k0r = kt + 4 * g + r;
      int k1r = k0r + 16;
      v0[r] = (k0r <= q) && (q - k0r < WIN_);
      v1[r] = (k1r <= q) && (q - k1r < WIN_);
      s0[r] = v0[r] ? s0[r] : -3.0e38f;
      s1[r] = v1[r] ? s1[r] : -3.0e38f;
      pmax = fmaxf(pmax, fmaxf(s0[r], s1[r]));
    }
    pmax = fmaxf(pmax, __shfl_xor(pmax, 16));
    pmax = fmaxf(pmax, __shfl_xor(pmax, 32));
    const float mnew = fmaxf(m, pmax);
    const float scale = __expf(m - mnew);
    float p0[4], p1[4], psum = 0.f;
    #pragma unroll
    for (int r = 0; r < 4; ++r) {
      p0[r] = v0[r] ? __expf(s0[r] - mnew) : 0.f;
      p1[r] = v1[r] ? __expf(s1[r] - mnew) : 0.f;
      psum += p0[r] + p1[r];
    }
    lsum = lsum * scale + psum;
    #pragma unroll
    for (int df = 0; df < 4; ++df) {
      o[df][0] *= scale; o[df][1] *= scale; o[df][2] *= scale; o[df][3] *= scale;
    }
    m = mnew;
    unsigned pk[4];
    #pragma unroll
    for (int r = 0; r < 4; ++r) pk[r] = (unsigned)f2bf(p0[r]) | ((unsigned)f2bf(p1[r]) << 16);
    const int srcLo = ((g & 1) << 1) * 16 + qcol;
    unsigned lo[4], hi[4];
    #pragma unroll
    for (int r = 0; r < 4; ++r) {
      lo[r] = (unsigned)__shfl((int)pk[r], srcLo);
      hi[r] = (unsigned)__shfl((int)pk[r], srcLo + 16);
    }
    const bool useHi = (g >= 2);
    union { unsigned u[4]; bf16x8 v; } bp;
    {
      unsigned e0 = useHi ? (lo[0] >> 16) : (lo[0] & 0xffffu);
      unsigned e1 = useHi ? (lo[1] >> 16) : (lo[1] & 0xffffu);
      unsigned e2 = useHi ? (lo[2] >> 16) : (lo[2] & 0xffffu);
      unsigned e3 = useHi ? (lo[3] >> 16) : (lo[3] & 0xffffu);
      unsigned e4 = useHi ? (hi[0] >> 16) : (hi[0] & 0xffffu);
      unsigned e5 = useHi ? (hi[1] >> 16) : (hi[1] & 0xffffu);
      unsigned e6 = useHi ? (hi[2] >> 16) : (hi[2] & 0xffffu);
      unsigned e7 = useHi ? (hi[3] >> 16) : (hi[3] & 0xffffu);
      bp.u[0] = e0 | (e1 << 16);
      bp.u[1] = e2 | (e3 << 16);
      bp.u[2] = e4 | (e5 << 16);
      bp.u[3] = e6 | (e7 << 16);
    }
    #pragma unroll
    for (int df = 0; df < 4; ++df) {
      bf16x8 vf = *(const bf16x8*)(Vp + (size_t)(16 * df + qcol) * S_ + kt + g * 8);
      o[df] = __builtin_amdgcn_mfma_f32_16x16x32_bf16(vf, bp.v, o[df], 0, 0, 0);
    }
  }
  lsum += __shfl_xor(lsum, 16);
  lsum += __shfl_xor(lsum, 32);
  const float inv = 1.f / lsum;
  bf16* Op = O + (size_t)(b * S_ + q) * (NH_ * HD_) + h * HD_;
  #pragma unroll
  for (int df = 0; df < 4; ++df) {
    ushort4 st = { f2bf(o[df][0] * inv), f2bf(o[df][1] * inv),
                   f2bf(o[df][2] * inv), f2bf(o[df][3] * inv) };
    *(ushort4*)((unsigned short*)Op + 16 * df + 4 * g) = st;
  }
}

// ---------------- silu(g)*u from packed gu -> bf16 ----------------
__global__ void silu_mul_kernel(const float* __restrict__ GU, unsigned short* __restrict__ out) {
  int idx = blockIdx.x * 256 + threadIdx.x;  // T_*256 exact
  int tok = idx >> 8, c = idx & 255;
  const float4 gv = *(const float4*)(GU + (size_t)tok * 2048 + c * 4);
  const float4 uv = *(const float4*)(GU + (size_t)tok * 2048 + 1024 + c * 4);
  ushort4 pk = { f2bf(silu_f(gv.x) * uv.x), f2bf(silu_f(gv.y) * uv.y),
                 f2bf(silu_f(gv.z) * uv.z), f2bf(silu_f(gv.w) * uv.w) };
  *(ushort4*)(out + (size_t)tok * 1024 + c * 4) = pk;
}

// ---------------- MoE FFN1 (MFMA, gathered rows, dual-B, 2-phase dbuf) ----------------
__global__ __launch_bounds__(256)
void moe_ffn1_kernel(const bf16* __restrict__ X, const bf16* __restrict__ W1t,
                     const bf16* __restrict__ W3t,
                     const int* __restrict__ counts, const int* __restrict__ entries,
                     bf16* __restrict__ Hb) {
  const int e = blockIdx.z;
  const int n_e = counts[e];
  const int r0 = blockIdx.y * 128;
  if (r0 >= n_e) return;
  const int f0 = blockIdx.x * 128;
  __shared__ char Al[2][8192], B1l[2][8192], B3l[2][8192];
  __shared__ int rowent[128];
  const int t = threadIdx.x;
  if (t < 128) { int r = r0 + t; rowent[t] = (r < n_e) ? entries[e * T_ + r] : -1; }
  __syncthreads();
  const int lane = t & 63, wid = t >> 6, wr = wid >> 1, wc = wid & 1;
  const int sr = t >> 2, sc = t & 3;
  const int c0 = sc ^ ((sr >> 1) & 3);
  const int c1 = sc ^ (((sr + 64) >> 1) & 3);
  int ea = rowent[sr], eb = rowent[sr + 64];
  const bf16* gA0 = X + (size_t)(ea < 0 ? 0 : (ea >> 1)) * H_ + c0 * 8;
  const bf16* gA1 = X + (size_t)(eb < 0 ? 0 : (eb >> 1)) * H_ + c1 * 8;
  const bf16* W1b = W1t + (size_t)e * F_ * H_;  // [F][H]
  const bf16* W3b = W3t + (size_t)e * F_ * H_;
  const bf16* gB10 = W1b + (size_t)(f0 + sr) * H_ + c0 * 8;
  const bf16* gB11 = W1b + (size_t)(f0 + sr + 64) * H_ + c1 * 8;
  const bf16* gB30 = W3b + (size_t)(f0 + sr) * H_ + c0 * 8;
  const bf16* gB31 = W3b + (size_t)(f0 + sr + 64) * H_ + c1 * 8;
  const int la = lane & 15, kg = lane >> 4;
  const int swz = (kg ^ ((la >> 1) & 3)) * 16;
  const int aoff = (wr * 64 + la) * 64 + swz;
  const int boff = (wc * 64 + la) * 64 + swz;
  auto STAGE = [&](int buf, int k0) {
    stage16(gA0 + k0, Al[buf] + t * 16);
    stage16(gA1 + k0, Al[buf] + 4096 + t * 16);
    stage16(gB10 + k0, B1l[buf] + t * 16);
    stage16(gB11 + k0, B1l[buf] + 4096 + t * 16);
    stage16(gB30 + k0, B3l[buf] + t * 16);
    stage16(gB31 + k0, B3l[buf] + 4096 + t * 16);
  };
  f32x4 acc1[4][4] = {}, acc3[4][4] = {};
  STAGE(0, 0);
  __syncthreads();
  for (int k0 = 0; k0 < H_; k0 += 32) {
    const int cur = (k0 >> 5) & 1;
    if (k0 + 32 < H_) STAGE(cur ^ 1, k0 + 32);
    bf16x8 af[4], b1f[4], b3f[4];
    #pragma unroll
    for (int i = 0; i < 4; ++i) af[i] = *(const bf16x8*)(Al[cur] + aoff + i * 1024);
    #pragma unroll
    for (int i = 0; i < 4; ++i) b1f[i] = *(const bf16x8*)(B1l[cur] + boff + i * 1024);
    #pragma unroll
    for (int i = 0; i < 4; ++i) b3f[i] = *(const bf16x8*)(B3l[cur] + boff + i * 1024);
    #pragma unroll
    for (int mi = 0; mi < 4; ++mi)
      #pragma unroll
      for (int ni = 0; ni < 4; ++ni) {
        acc1[mi][ni] = __builtin_amdgcn_mfma_f32_16x16x32_bf16(af[mi], b1f[ni], acc1[mi][ni], 0, 0, 0);
        acc3[mi][ni] = __builtin_amdgcn_mfma_f32_16x16x32_bf16(af[mi], b3f[ni], acc3[mi][ni], 0, 0, 0);
      }
    __syncthreads();
  }
  #pragma unroll
  for (int mi = 0; mi < 4; ++mi) {
    int rloc = wr * 64 + mi * 16 + kg * 4;
    #pragma unroll
    for (int ni = 0; ni < 4; ++ni) {
      int col = f0 + wc * 64 + ni * 16 + la;
      #pragma unroll
      for (int r = 0; r < 4; ++r) {
        int ent = rowent[rloc + r];
        if (ent < 0) continue;
        float gv = acc1[mi][ni][r], uv = acc3[mi][ni][r];
        Hb[(size_t)ent * F_ + col] = __float2bfloat16(silu_f(gv) * uv);
      }
    }
  }
}

// ---------------- MoE FFN2 (MFMA, gathered rows, 2-phase dbuf) ----------------
__global__ __launch_bounds__(256)
void moe_ffn2_kernel(const bf16* __restrict__ Hb, const bf16* __restrict__ W2t,
                     const int* __restrict__ counts, const int* __restrict__ entries,
                     float* __restrict__ Y) {
  const int e = blockIdx.z;
  const int n_e = counts[e];
  const int r0 = blockIdx.y * 128;
  if (r0 >= n_e) return;
  const int n0 = blockIdx.x * 128;
  __shared__ char Al[2][8192], Bl[2][8192];
  __shared__ int rowent[128];
  const int t = threadIdx.x;
  if (t < 128) { int r = r0 + t; rowent[t] = (r < n_e) ? entries[e * T_ + r] : -1; }
  __syncthreads();
  const int lane = t & 63, wid = t >> 6, wr = wid >> 1, wc = wid & 1;
  const int sr = t >> 2, sc = t & 3;
  const int c0 = sc ^ ((sr >> 1) & 3);
  const int c1 = sc ^ (((sr + 64) >> 1) & 3);
  int ea = rowent[sr], eb = rowent[sr + 64];
  const bf16* gA0 = Hb + (size_t)(ea < 0 ? 0 : ea) * F_ + c0 * 8;
  const bf16* gA1 = Hb + (size_t)(eb < 0 ? 0 : eb) * F_ + c1 * 8;
  const bf16* W2b = W2t + (size_t)e * H_ * F_;  // [H][F]
  const bf16* gB0 = W2b + (size_t)(n0 + sr) * F_ + c0 * 8;
  const bf16* gB1 = W2b + (size_t)(n0 + sr + 64) * F_ + c1 * 8;
  const int la = lane & 15, kg = lane >> 4;
  const int swz = (kg ^ ((la >> 1) & 3)) * 16;
  const int aoff = (wr * 64 + la) * 64 + swz;
  const int boff = (wc * 64 + la) * 64 + swz;
  auto STAGE = [&](int buf, int k0) {
    stage16(gA0 + k0, Al[buf] + t * 16);
    stage16(gA1 + k0, Al[buf] + 4096 + t * 16);
    stage16(gB0 + k0, Bl[buf] + t * 16);
    stage16(gB1 + k0, Bl[buf] + 4096 + t * 16);
  };
  f32x4 acc[4][4] = {};
  STAGE(0, 0);
  __syncthreads();
  for (int k0 = 0; k0 < F_; k0 += 32) {
    const int cur = (k0 >> 5) & 1;
    if (k0 + 32 < F_) STAGE(cur ^ 1, k0 + 32);
    bf16x8 af[4], bfr[4];
    #pragma unroll
    for (int i = 0; i < 4; ++i) af[i] = *(const bf16x8*)(Al[cur] + aoff + i * 1024);
    #pragma unroll
    for (int i = 0; i < 4; ++i) bfr[i] = *(const bf16x8*)(Bl[cur] + boff + i * 1024);
    #pragma unroll
    for (int mi = 0; mi < 4; ++mi)
      #pragma unroll
      for (int ni = 0; ni < 4; ++ni)
        acc[mi][ni] = __builtin_amdgcn_mfma_f32_16x16x32_bf16(af[mi], bfr[ni], acc[mi][ni], 0, 0, 0);
    __syncthreads();
  }
  #pragma unroll
  for (int mi = 0; mi < 4; ++mi) {
    int rloc = wr * 64 + mi * 16 + kg * 4;
    #pragma unroll
    for (int ni = 0; ni < 4; ++ni) {
      int col = n0 + wc * 64 + ni * 16 + la;
      #pragma unroll
      for (int r = 0; r < 4; ++r) {
        int ent = rowent[rloc + r];
        if (ent < 0) continue;
        Y[(size_t)ent * H_ + col] = acc[mi][ni][r];
      }
    }
  }
}

// ---------------- combine: out[t] += w0*Y[2t] + w1*Y[2t+1] ----------------
__global__ void combine_kernel(const float* __restrict__ Y, const float* __restrict__ wgt,
                               float* __restrict__ out) {
  int t = blockIdx.x;
  int c = threadIdx.x;  // 256
  float w0 = wgt[t * 2], w1 = wgt[t * 2 + 1];
  float4 y0 = *(const float4*)(&Y[((size_t)t * 2) * H_ + c * 4]);
  float4 y1 = *(const float4*)(&Y[((size_t)t * 2 + 1) * H_ + c * 4]);
  float4 o  = *(float4*)(&out[(size_t)t * H_ + c * 4]);
  o.x += w0 * y0.x + w1 * y1.x;
  o.y += w0 * y0.y + w1 * y1.y;
  o.z += w0 * y0.z + w1 * y1.z;
  o.w += w0 * y0.w + w1 * y1.w;
  *(float4*)(&out[(size_t)t * H_ + c * 4]) = o;
}

extern "C" void kernel_launch(void* const* d_in, const int* in_sizes, int n_in,
                              void* d_out, int out_size, void* d_ws, size_t ws_size,
                              hipStream_t stream) {
  const float* hidden    = (const float*)d_in[0];
  const float* ln1_w     = (const float*)d_in[1];
  const float* q_w       = (const float*)d_in[2];
  const float* k_w       = (const float*)d_in[3];
  const float* v_w       = (const float*)d_in[4];
  const float* o_w       = (const float*)d_in[5];
  const float* res_ln_w  = (const float*)d_in[6];
  const float* rw1       = (const float*)d_in[7];
  const float* rw3       = (const float*)d_in[8];
  const float* rw2       = (const float*)d_in[9];
  const float* post_ln_w = (const float*)d_in[10];
  const float* gate_w    = (const float*)d_in[11];
  const float* e_w1      = (const float*)d_in[12];
  const float* e_w3      = (const float*)d_in[13];
  const float* e_w2      = (const float*)d_in[14];
  float* out = (float*)d_out;

  char* base = (char*)d_ws;
  size_t off = 0;
  auto alloc = [&](size_t bytes) -> void* {
    void* p = base + off;
    off += (bytes + 255) & ~(size_t)255;
    return p;
  };
  float* qkvf   = (float*)alloc((size_t)T_ * QKVN_ * 4);
  float* costab = (float*)alloc((size_t)S_ * 32 * 4);
  float* sintab = (float*)alloc((size_t)S_ * 32 * 4);
  float* resat  = (float*)alloc((size_t)T_ * H_ * 4);
  float* gu     = (float*)alloc((size_t)T_ * 2048 * 4);
  float* wgt    = (float*)alloc((size_t)T_ * 2 * 4);
  float* Y      = (float*)alloc((size_t)T_ * 2 * H_ * 4);
  bf16* h1b     = (bf16*)alloc((size_t)T_ * H_ * 2);
  bf16* h2b     = (bf16*)alloc((size_t)T_ * H_ * 2);
  bf16* h3b     = (bf16*)alloc((size_t)T_ * H_ * 2);
  bf16* attnb   = (bf16*)alloc((size_t)T_ * H_ * 2);
  bf16* gb      = (bf16*)alloc((size_t)T_ * H_ * 2);
  bf16* Hb      = (bf16*)alloc((size_t)T_ * 2 * F_ * 2);
  bf16* Qbuf    = (bf16*)alloc((size_t)B_ * NH_ * S_ * HD_ * 2);
  bf16* Kbuf    = (bf16*)alloc((size_t)B_ * NKV_ * S_ * HD_ * 2);
  bf16* Vtbuf   = (bf16*)alloc((size_t)B_ * NKV_ * HD_ * S_ * 2);
  bf16* qkvwt   = (bf16*)alloc((size_t)QKVN_ * H_ * 2);
  bf16* owt     = (bf16*)alloc((size_t)H_ * H_ * 2);
  bf16* w13t    = (bf16*)alloc((size_t)2048 * H_ * 2);
  bf16* rw2t    = (bf16*)alloc((size_t)H_ * H_ * 2);
  bf16* ew1t    = (bf16*)alloc((size_t)E_ * F_ * H_ * 2);
  bf16* ew3t    = (bf16*)alloc((size_t)E_ * F_ * H_ * 2);
  bf16* ew2t    = (bf16*)alloc((size_t)E_ * H_ * F_ * 2);
  int* counts   = (int*)alloc(64);
  int* entries  = (int*)alloc((size_t)E_ * T_ * 4);

  rope_table_kernel<<<(S_ * 32 + 255) / 256, 256, 0, stream>>>(costab, sintab, counts);

  // weight prep: fp32 [K][N] -> bf16 [N][K]; five 1024x1024 in ONE launch
  {
    TransBatch tb;
    tb.src[0] = q_w;  tb.dst[0] = qkvwt;
    tb.src[1] = o_w;  tb.dst[1] = owt;
    tb.src[2] = rw1;  tb.dst[2] = w13t;
    tb.src[3] = rw3;  tb.dst[3] = w13t + (size_t)1024 * 1024;
    tb.src[4] = rw2;  tb.dst[4] = rw2t;
    transpose_cvt5_kernel<<<dim3(32, 32, 5), 256, 0, stream>>>(tb, 1024, 1024);
  }
  {
    TransBatch tb = {};
    tb.src[0] = k_w;  tb.dst[0] = qkvwt + (size_t)1024 * 1024;
    tb.src[1] = v_w;  tb.dst[1] = qkvwt + (size_t)1280 * 1024;
    transpose_cvt5_kernel<<<dim3(32, 8, 2), 256, 0, stream>>>(tb, 1024, 256);
  }
  transpose_cvt_kernel<<<dim3(32, 88, 8), 256, 0, stream>>>(e_w1, ew1t, 1024, 2816);
  transpose_cvt_kernel<<<dim3(32, 88, 8), 256, 0, stream>>>(e_w3, ew3t, 1024, 2816);
  transpose_cvt_kernel<<<dim3(88, 32, 8), 256, 0, stream>>>(e_w2, ew2t, 2816, 1024);

  // attention path
  rms_kernel<<<T_, 256, 0, stream>>>(hidden, ln1_w, h1b);
  mm_kernel<64, false><<<dim3(QKVN_ / 64, T_ / 128), 256, 0, stream>>>(h1b, qkvwt, nullptr, qkvf, T_, QKVN_, H_);
  rope_cvt_qk_kernel<<<(T_ * 20 * 32) / 256, 256, 0, stream>>>(qkvf, costab, sintab, Qbuf, Kbuf);
  vt_kernel<<<dim3(32, 2, 8), 256, 0, stream>>>(qkvf, Vtbuf);
  attn_kernel<<<dim3(S_ / 64, NH_, B_), 256, 0, stream>>>(Qbuf, Kbuf, Vtbuf, attnb);
  mm_kernel<64, true><<<dim3(16, 16), 256, 0, stream>>>(attnb, owt, hidden, resat, T_, H_, H_);

  // parallel residual dense MLP
  rms_kernel<<<T_, 256, 0, stream>>>(resat, res_ln_w, h2b);
  mm_kernel<128, false><<<dim3(16, 16), 256, 0, stream>>>(h2b, w13t, nullptr, gu, T_, 2048, H_);
  silu_mul_kernel<<<T_, 256, 0, stream>>>(gu, (unsigned short*)gb);
  mm_kernel<64, true><<<dim3(16, 16), 256, 0, stream>>>(gb, rw2t, resat, out, T_, H_, H_);

  // MoE path on the ORIGINAL layer input (fused RMS + gate)
  rms_gate_kernel<<<T_, 256, 0, stream>>>(hidden, post_ln_w, gate_w, h3b, counts, entries, wgt);
  moe_ffn1_kernel<<<dim3(F_ / 128, 16, E_), 256, 0, stream>>>(h3b, ew1t, ew3t, counts, entries, Hb);
  moe_ffn2_kernel<<<dim3(8, 16, E_), 256, 0, stream>>>(Hb, ew2t, counts, entries, Y);
  combine_kernel<<<T_, 256, 0, stream>>>(Y, wgt, out);
}

// Round 11
// 703.281 us; speedup vs baseline: 1.5170x; 1.0655x over previous
//
#include <hip/hip_runtime.h>
#include <hip/hip_bf16.h>
#include <math.h>

// Problem constants (Arctic decoder layer)
#define B_    2
#define S_    1024
#define H_    1024
#define NH_   16
#define NKV_  4
#define HD_   64
#define F_    2816
#define E_    8
#define WIN_  256
#define T_    (B_*S_)
#define EPS_  1e-5f
#define QKVN_ 1536

typedef __hip_bfloat16 bf16;
using f32x4  = __attribute__((ext_vector_type(4))) float;
using bf16x8 = __attribute__((ext_vector_type(8))) short;

__device__ __forceinline__ float silu_f(float x) { return x / (1.0f + expf(-x)); }

__device__ __forceinline__ unsigned short f2bf(float v) {
  __hip_bfloat16 b = __float2bfloat16(v);
  return *reinterpret_cast<unsigned short*>(&b);
}

// async global->LDS 16B stage (linear LDS dst: wave-uniform base + lane*16)
__device__ __forceinline__ void stage16(const void* g, void* l) {
#if defined(__has_builtin) && __has_builtin(__builtin_amdgcn_global_load_lds)
  __builtin_amdgcn_global_load_lds((const __attribute__((address_space(1))) unsigned int*)g,
                                   (__attribute__((address_space(3))) unsigned int*)l,
                                   16, 0, 0);
#else
  *(float4*)l = *(const float4*)g;
#endif
}

// ---------------- RoPE tables (+ zero MoE counters, fused) ----------------
__global__ void rope_table_kernel(float* __restrict__ costab, float* __restrict__ sintab,
                                  int* __restrict__ counts) {
  int idx = blockIdx.x * blockDim.x + threadIdx.x;  // S_*32
  if (blockIdx.x == 0 && threadIdx.x < E_) counts[threadIdx.x] = 0;
  if (idx >= S_ * 32) return;
  int s = idx >> 5, j = idx & 31;
  float inv = powf(10000.0f, -(float)j / 32.0f);
  float ang = (float)s * inv;
  costab[idx] = cosf(ang);
  sintab[idx] = sinf(ang);
}

// ---------------- transpose + fp32->bf16: src[K][N] -> dst[N][K] ----------------
__global__ void transpose_cvt_kernel(const float* __restrict__ src, bf16* __restrict__ dst,
                                     int K, int N) {
  __shared__ float tile[32][33];
  const size_t bstride = (size_t)K * N;
  src += bstride * blockIdx.z;
  dst += bstride * blockIdx.z;
  int bk = blockIdx.x * 32, bn = blockIdx.y * 32;
  int tx = threadIdx.x & 31, ty = threadIdx.x >> 5;  // 256 thr: ty 0..7
  #pragma unroll
  for (int i = 0; i < 4; ++i)
    tile[ty + i * 8][tx] = src[(size_t)(bk + ty + i * 8) * N + bn + tx];
  __syncthreads();
  #pragma unroll
  for (int i = 0; i < 4; ++i)
    dst[(size_t)(bn + ty + i * 8) * K + bk + tx] = __float2bfloat16(tile[tx][ty + i * 8]);
}

// variant B: z selects (src,dst) pair from a pointer batch (distinct weights, one launch)
struct TransBatch { const float* src[5]; bf16* dst[5]; };
__global__ void transpose_cvt5_kernel(TransBatch tb, int K, int N) {
  __shared__ float tile[32][33];
  const float* src = tb.src[blockIdx.z];
  bf16* dst = tb.dst[blockIdx.z];
  int bk = blockIdx.x * 32, bn = blockIdx.y * 32;
  int tx = threadIdx.x & 31, ty = threadIdx.x >> 5;
  #pragma unroll
  for (int i = 0; i < 4; ++i)
    tile[ty + i * 8][tx] = src[(size_t)(bk + ty + i * 8) * N + bn + tx];
  __syncthreads();
  #pragma unroll
  for (int i = 0; i < 4; ++i)
    dst[(size_t)(bn + ty + i * 8) * K + bk + tx] = __float2bfloat16(tile[tx][ty + i * 8]);
}

// ---------------- RMSNorm: fp32 in -> bf16 out ----------------
__global__ void rms_kernel(const float* __restrict__ x, const float* __restrict__ w,
                           bf16* __restrict__ ob) {
  const int row = blockIdx.x, t = threadIdx.x;  // 256
  const float* xr = x + (size_t)row * H_;
  float4 v = *(const float4*)(&xr[t * 4]);
  float ss = v.x*v.x + v.y*v.y + v.z*v.z + v.w*v.w;
  #pragma unroll
  for (int o = 32; o > 0; o >>= 1) ss += __shfl_xor(ss, o);
  __shared__ float red[4];
  if ((t & 63) == 0) red[t >> 6] = ss;
  __syncthreads();
  float tot = red[0] + red[1] + red[2] + red[3];
  float scale = rsqrtf(tot * (1.0f / H_) + EPS_);
  float4 wv = *(const float4*)(&w[t * 4]);
  ushort4 pk = { f2bf(v.x*scale*wv.x), f2bf(v.y*scale*wv.y),
                 f2bf(v.z*scale*wv.z), f2bf(v.w*scale*wv.w) };
  *(ushort4*)((unsigned short*)ob + (size_t)row * H_ + t * 4) = pk;
}

// ---------------- fused RMSNorm + MoE gate (fp32 logits, top-2, compact lists) ----------------
__global__ void rms_gate_kernel(const float* __restrict__ x, const float* __restrict__ w,
                                const float* __restrict__ gw, bf16* __restrict__ ob,
                                int* __restrict__ counts, int* __restrict__ entries,
                                float* __restrict__ wgt) {
  const int row = blockIdx.x, t = threadIdx.x;  // 256
  const float* xr = x + (size_t)row * H_;
  float4 v = *(const float4*)(&xr[t * 4]);
  float ss = v.x*v.x + v.y*v.y + v.z*v.z + v.w*v.w;
  #pragma unroll
  for (int o = 32; o > 0; o >>= 1) ss += __shfl_xor(ss, o);
  __shared__ float red[4];
  __shared__ float sm[4][8];
  if ((t & 63) == 0) red[t >> 6] = ss;
  __syncthreads();
  float tot = red[0] + red[1] + red[2] + red[3];
  float scale = rsqrtf(tot * (1.0f / H_) + EPS_);
  float4 wv = *(const float4*)(&w[t * 4]);
  float o0 = v.x*scale*wv.x, o1 = v.y*scale*wv.y, o2 = v.z*scale*wv.z, o3 = v.w*scale*wv.w;
  ushort4 pk = { f2bf(o0), f2bf(o1), f2bf(o2), f2bf(o3) };
  *(ushort4*)((unsigned short*)ob + (size_t)row * H_ + t * 4) = pk;
  const float* gr = gw + (size_t)(t * 4) * E_;
  float acc[E_];
  #pragma unroll
  for (int e = 0; e < E_; ++e)
    acc[e] = o0 * gr[e] + o1 * gr[E_ + e] + o2 * gr[2 * E_ + e] + o3 * gr[3 * E_ + e];
  #pragma unroll
  for (int e = 0; e < E_; ++e) {
    #pragma unroll
    for (int o = 32; o > 0; o >>= 1) acc[e] += __shfl_xor(acc[e], o);
  }
  if ((t & 63) == 0) {
    #pragma unroll
    for (int e = 0; e < E_; ++e) sm[t >> 6][e] = acc[e];
  }
  __syncthreads();
  if (t == 0) {
    float lg[E_];
    #pragma unroll
    for (int e = 0; e < E_; ++e) lg[e] = sm[0][e] + sm[1][e] + sm[2][e] + sm[3][e];
    float m = lg[0];
    #pragma unroll
    for (int e = 1; e < E_; ++e) m = fmaxf(m, lg[e]);
    float p[E_];
    #pragma unroll
    for (int e = 0; e < E_; ++e) p[e] = expf(lg[e] - m);
    int i0 = 0; float b0 = p[0];
    #pragma unroll
    for (int e = 1; e < E_; ++e) if (p[e] > b0) { b0 = p[e]; i0 = e; }
    int i1 = -1; float b1 = -1.f;
    #pragma unroll
    for (int e = 0; e < E_; ++e) if (e != i0 && p[e] > b1) { b1 = p[e]; i1 = e; }
    float inv = 1.f / (b0 + b1);
    wgt[row * 2 + 0] = b0 * inv;
    wgt[row * 2 + 1] = b1 * inv;
    int pos0 = atomicAdd(&counts[i0], 1);
    entries[i0 * T_ + pos0] = row * 2 + 0;
    int pos1 = atomicAdd(&counts[i1], 1);
    entries[i1 * T_ + pos1] = row * 2 + 1;
  }
}

// =====================================================================
// bf16 MFMA GEMM with COUNTED-vmcnt 2-phase pipeline (T3+T4 minimum).
// =====================================================================
template <int BN, bool ADD_RES>
__global__ __launch_bounds__(256)
void mm_kernel(const bf16* __restrict__ A, const bf16* __restrict__ Bt,
               const float* __restrict__ Res, float* __restrict__ C,
               int M, int N, int K) {
  __shared__ char Al[2][8192];
  __shared__ char Bl[2][BN * 64];
  constexpr int NL = (BN == 128) ? 4 : 3;
  const int t = threadIdx.x;
  const int m0 = blockIdx.y * 128, n0 = blockIdx.x * BN;
  const int lane = t & 63, wid = t >> 6;
  const int wr = wid >> 1, wc = wid & 1;
  const int sr = t >> 2, sc = t & 3;
  const int cA0 = sc ^ ((sr >> 1) & 3);
  const int cA1 = sc ^ (((sr + 64) >> 1) & 3);
  const bf16* gA0 = A + (size_t)(m0 + sr) * K + cA0 * 8;
  const bf16* gA1 = A + (size_t)(m0 + sr + 64) * K + cA1 * 8;
  const bf16* gB0 = Bt + (size_t)(n0 + sr) * K + cA0 * 8;
  const bf16* gB1 = Bt + (size_t)(n0 + sr + 64) * K + cA1 * 8;  // unused if BN==64
  const int la = lane & 15, kg = lane >> 4;
  const int swz = (kg ^ ((la >> 1) & 3)) * 16;
  const int aoff = (wr * 64 + la) * 64 + swz;
  constexpr int NW = BN / 32;
  const int boff = (wc * (BN / 2) + la) * 64 + swz;
  auto STAGE = [&](int buf, int k0) {
    stage16(gA0 + k0, Al[buf] + t * 16);
    stage16(gA1 + k0, Al[buf] + 4096 + t * 16);
    stage16(gB0 + k0, Bl[buf] + t * 16);
    if constexpr (BN == 128) stage16(gB1 + k0, Bl[buf] + 4096 + t * 16);
  };
  f32x4 acc[4][NW] = {};
  STAGE(0, 0);
  for (int k0 = 0; k0 < K; k0 += 32) {
    const int cur = (k0 >> 5) & 1;
    if (k0 + 32 < K) {
      STAGE(cur ^ 1, k0 + 32);
      asm volatile("s_waitcnt vmcnt(%0)" :: "n"(NL) : "memory");
    } else {
      asm volatile("s_waitcnt vmcnt(0)" ::: "memory");
    }
    __builtin_amdgcn_s_barrier();
    bf16x8 af[4], bfr[NW];
    #pragma unroll
    for (int i = 0; i < 4; ++i) af[i] = *(const bf16x8*)(Al[cur] + aoff + i * 1024);
    #pragma unroll
    for (int i = 0; i < NW; ++i) bfr[i] = *(const bf16x8*)(Bl[cur] + boff + i * 1024);
    #pragma unroll
    for (int mi = 0; mi < 4; ++mi)
      #pragma unroll
      for (int ni = 0; ni < NW; ++ni)
        acc[mi][ni] = __builtin_amdgcn_mfma_f32_16x16x32_bf16(af[mi], bfr[ni], acc[mi][ni], 0, 0, 0);
    __builtin_amdgcn_s_barrier();
  }
  #pragma unroll
  for (int mi = 0; mi < 4; ++mi) {
    int row = m0 + wr * 64 + mi * 16 + kg * 4;
    #pragma unroll
    for (int ni = 0; ni < NW; ++ni) {
      int col = n0 + wc * (BN / 2) + ni * 16 + la;
      #pragma unroll
      for (int r = 0; r < 4; ++r) {
        size_t off = (size_t)(row + r) * N + col;
        float v = acc[mi][ni][r];
        if (ADD_RES) v += Res[off];
        C[off] = v;
      }
    }
  }
}

// =====================================================================
// Dense dual-B GEMM + fused silu: Out = bf16(silu(X@rw1) * (X@rw3)).
// Clone of moe_ffn1 without the gather. 128x64 tile, counted vmcnt.
// W13t: rw1^T rows [0..1023], rw3^T rows [1024..2047], each [N][K].
// =====================================================================
__global__ __launch_bounds__(256)
void mlp13_kernel(const bf16* __restrict__ X, const bf16* __restrict__ W13t,
                  bf16* __restrict__ Out) {
  const int m0 = blockIdx.y * 128, f0 = blockIdx.x * 64;
  __shared__ char Al[2][8192], B1l[2][4096], B3l[2][4096];
  const int t = threadIdx.x;
  const int lane = t & 63, wid = t >> 6, wr = wid >> 1, wc = wid & 1;
  const int sr = t >> 2, sc = t & 3;
  const int c0 = sc ^ ((sr >> 1) & 3);
  const int c1 = sc ^ (((sr + 64) >> 1) & 3);
  const bf16* gA0 = X + (size_t)(m0 + sr) * H_ + c0 * 8;
  const bf16* gA1 = X + (size_t)(m0 + sr + 64) * H_ + c1 * 8;
  const bf16* gB1 = W13t + (size_t)(f0 + sr) * H_ + c0 * 8;
  const bf16* gB3 = W13t + (size_t)(1024 + f0 + sr) * H_ + c0 * 8;
  const int la = lane & 15, kg = lane >> 4;
  const int swz = (kg ^ ((la >> 1) & 3)) * 16;
  const int aoff = (wr * 64 + la) * 64 + swz;
  const int boff = (wc * 32 + la) * 64 + swz;
  auto STAGE = [&](int buf, int k0) {
    stage16(gA0 + k0, Al[buf] + t * 16);
    stage16(gA1 + k0, Al[buf] + 4096 + t * 16);
    stage16(gB1 + k0, B1l[buf] + t * 16);
    stage16(gB3 + k0, B3l[buf] + t * 16);
  };
  f32x4 acc1[4][2] = {}, acc3[4][2] = {};
  STAGE(0, 0);
  for (int k0 = 0; k0 < H_; k0 += 32) {
    const int cur = (k0 >> 5) & 1;
    if (k0 + 32 < H_) {
      STAGE(cur ^ 1, k0 + 32);
      asm volatile("s_waitcnt vmcnt(4)" ::: "memory");
    } else {
      asm volatile("s_waitcnt vmcnt(0)" ::: "memory");
    }
    __builtin_amdgcn_s_barrier();
    bf16x8 af[4], b1f[2], b3f[2];
    #pragma unroll
    for (int i = 0; i < 4; ++i) af[i] = *(const bf16x8*)(Al[cur] + aoff + i * 1024);
    #pragma unroll
    for (int i = 0; i < 2; ++i) b1f[i] = *(const bf16x8*)(B1l[cur] + boff + i * 1024);
    #pragma unroll
    for (int i = 0; i < 2; ++i) b3f[i] = *(const bf16x8*)(B3l[cur] + boff + i * 1024);
    #pragma unroll
    for (int mi = 0; mi < 4; ++mi)
      #pragma unroll
      for (int ni = 0; ni < 2; ++ni) {
        acc1[mi][ni] = __builtin_amdgcn_mfma_f32_16x16x32_bf16(af[mi], b1f[ni], acc1[mi][ni], 0, 0, 0);
        acc3[mi][ni] = __builtin_amdgcn_mfma_f32_16x16x32_bf16(af[mi], b3f[ni], acc3[mi][ni], 0, 0, 0);
      }
    __builtin_amdgcn_s_barrier();
  }
  #pragma unroll
  for (int mi = 0; mi < 4; ++mi) {
    int row = m0 + wr * 64 + mi * 16 + kg * 4;
    #pragma unroll
    for (int ni = 0; ni < 2; ++ni) {
      int col = f0 + wc * 32 + ni * 16 + la;
      #pragma unroll
      for (int r = 0; r < 4; ++r)
        Out[(size_t)(row + r) * 1024 + col] = __float2bfloat16(silu_f(acc1[mi][ni][r]) * acc3[mi][ni][r]);
    }
  }
}

// ---------------- RoPE + cvt, merged Q and K (head 0..19) ----------------
__global__ void rope_cvt_qk_kernel(const float* __restrict__ QKV, const float* __restrict__ ct,
                                   const float* __restrict__ st, bf16* __restrict__ Qb,
                                   bf16* __restrict__ Kb) {
  int idx = blockIdx.x * 256 + threadIdx.x;  // T_*20*32
  int j = idx & 31;
  int hh = (idx >> 5) % 20;
  int t = idx / (32 * 20);
  int s = t & (S_ - 1), b = t >> 10;
  float c = ct[s * 32 + j], sn = st[s * 32 + j];
  if (hh < NH_) {
    const float* src = QKV + (size_t)t * QKVN_ + hh * HD_;
    float x1 = src[j], x2 = src[j + 32];
    bf16* dst = Qb + ((size_t)(b * NH_ + hh) * S_ + s) * HD_;
    dst[j]      = __float2bfloat16((x1 * c - x2 * sn) * 0.125f);
    dst[j + 32] = __float2bfloat16((x2 * c + x1 * sn) * 0.125f);
  } else {
    int kvh = hh - NH_;
    const float* src = QKV + (size_t)t * QKVN_ + 1024 + kvh * HD_;
    float x1 = src[j], x2 = src[j + 32];
    bf16* dst = Kb + ((size_t)(b * NKV_ + kvh) * S_ + s) * HD_;
    dst[j]      = __float2bfloat16(x1 * c - x2 * sn);
    dst[j + 32] = __float2bfloat16(x2 * c + x1 * sn);
  }
}

// ---------------- V transpose: qkvf V section -> Vt[b][kvh][d][s] bf16 ----------------
__global__ void vt_kernel(const float* __restrict__ QKV, bf16* __restrict__ Vt) {
  int p = blockIdx.z;  // b*NKV+kvh
  int b = p >> 2, kvh = p & 3;
  int s0 = blockIdx.x * 32, d0 = blockIdx.y * 32;
  __shared__ float tile[32][33];
  int tx = threadIdx.x & 31, ty = threadIdx.x >> 5;
  const float* src = QKV + (size_t)(b * S_) * QKVN_ + 1280 + kvh * HD_;
  #pragma unroll
  for (int i = 0; i < 4; ++i)
    tile[ty + i * 8][tx] = src[(size_t)(s0 + ty + i * 8) * QKVN_ + d0 + tx];
  __syncthreads();
  bf16* dst = Vt + (size_t)p * HD_ * S_;
  #pragma unroll
  for (int i = 0; i < 4; ++i)
    dst[(size_t)(d0 + ty + i * 8) * S_ + s0 + tx] = __float2bfloat16(tile[tx][ty + i * 8]);
}

// =====================================================================
// MFMA flash attention, sliding window. 1 wave = 16 queries of one (b,h).
// =====================================================================
__global__ __launch_bounds__(256)
void attn_kernel(const bf16* __restrict__ Qb, const bf16* __restrict__ Kb,
                 const bf16* __restrict__ Vt, bf16* __restrict__ O) {
  const int w = threadIdx.x >> 6, lane = threadIdx.x & 63;
  const int qw = blockIdx.x * 64 + w * 16;
  const int h = blockIdx.y, b = blockIdx.z, kvh = h >> 2;
  const int g = lane >> 4, qcol = lane & 15;
  const bf16* Qp = Qb + ((size_t)(b * NH_ + h) * S_ + qw) * HD_;
  const bf16* Kp = Kb + (size_t)(b * NKV_ + kvh) * S_ * HD_;
  const bf16* Vp = Vt + (size_t)(b * NKV_ + kvh) * HD_ * S_;
  const bf16x8 qf0 = *(const bf16x8*)(Qp + qcol * HD_ + g * 8);
  const bf16x8 qf1 = *(const bf16x8*)(Qp + qcol * HD_ + 32 + g * 8);
  const int q = qw + qcol;
  float m = -3.0e38f, lsum = 0.f;
  f32x4 o[4] = {};
  int kstart = qw - (WIN_ - 1); if (kstart < 0) kstart = 0; kstart &= ~31;
  const int kend = qw + 16;
  for (int kt = kstart; kt < kend; kt += 32) {
    f32x4 s0 = {}, s1 = {};
    {
      const bf16* kr0 = Kp + (size_t)(kt + qcol) * HD_ + g * 8;
      const bf16* kr1 = kr0 + 16 * HD_;
      bf16x8 kf;
      kf = *(const bf16x8*)(kr0);      s0 = __builtin_amdgcn_mfma_f32_16x16x32_bf16(kf, qf0, s0, 0, 0, 0);
      kf = *(const bf16x8*)(kr0 + 32); s0 = __builtin_amdgcn_mfma_f32_16x16x32_bf16(kf, qf1, s0, 0, 0, 0);
      kf = *(const bf16x8*)(kr1);      s1 = __builtin_amdgcn_mfma_f32_16x16x32_bf16(kf, qf0, s1, 0, 0, 0);
      kf = *(const bf16x8*)(kr1 + 32); s1 = __builtin_amdgcn_mfma_f32_16x16x32_bf16(kf, qf1, s1, 0, 0, 0);
    }
    bool v0[4], v1[4];
    float pmax = -3.0e38f;
    #pragma unroll
    for (int r = 0; r < 4; ++r) {
      int k0r = kt + 4 * g + r;
      int k1r = k0r + 16;
      v0[r] = (k0r <= q) && (q - k0r < WIN_);
      v1[r] = (k1r <= q) && (q - k1r < WIN_);
      s0[r] = v0[r] ? s0[r] : -3.0e38f;
      s1[r] = v1[r] ? s1[r] : -3.0e38f;
      pmax = fmaxf(pmax, fmaxf(s0[r], s1[r]));
    }
    pmax = fmaxf(pmax, __shfl_xor(pmax, 16));
    pmax = fmaxf(pmax, __shfl_xor(pmax, 32));
    const float mnew = fmaxf(m, pmax);
    const float scale = __expf(m - mnew);
    float p0[4], p1[4], psum = 0.f;
    #pragma unroll
    for (int r = 0; r < 4; ++r) {
      p0[r] = v0[r] ? __expf(s0[r] - mnew) : 0.f;
      p1[r] = v1[r] ? __expf(s1[r] - mnew) : 0.f;
      psum += p0[r] + p1[r];
    }
    lsum = lsum * scale + psum;
    #pragma unroll
    for (int df = 0; df < 4; ++df) {
      o[df][0] *= scale; o[df][1] *= scale; o[df][2] *= scale; o[df][3] *= scale;
    }
    m = mnew;
    unsigned pk[4];
    #pragma unroll
    for (int r = 0; r < 4; ++r) pk[r] = (unsigned)f2bf(p0[r]) | ((unsigned)f2bf(p1[r]) << 16);
    const int srcLo = ((g & 1) << 1) * 16 + qcol;
    unsigned lo[4], hi[4];
    #pragma unroll
    for (int r = 0; r < 4; ++r) {
      lo[r] = (unsigned)__shfl((int)pk[r], srcLo);
      hi[r] = (unsigned)__shfl((int)pk[r], srcLo + 16);
    }
    const bool useHi = (g >= 2);
    union { unsigned u[4]; bf16x8 v; } bp;
    {
      unsigned e0 = useHi ? (lo[0] >> 16) : (lo[0] & 0xffffu);
      unsigned e1 = useHi ? (lo[1] >> 16) : (lo[1] & 0xffffu);
      unsigned e2 = useHi ? (lo[2] >> 16) : (lo[2] & 0xffffu);
      unsigned e3 = useHi ? (lo[3] >> 16) : (lo[3] & 0xffffu);
      unsigned e4 = useHi ? (hi[0] >> 16) : (hi[0] & 0xffffu);
      unsigned e5 = useHi ? (hi[1] >> 16) : (hi[1] & 0xffffu);
      unsigned e6 = useHi ? (hi[2] >> 16) : (hi[2] & 0xffffu);
      unsigned e7 = useHi ? (hi[3] >> 16) : (hi[3] & 0xffffu);
      bp.u[0] = e0 | (e1 << 16);
      bp.u[1] = e2 | (e3 << 16);
      bp.u[2] = e4 | (e5 << 16);
      bp.u[3] = e6 | (e7 << 16);
    }
    #pragma unroll
    for (int df = 0; df < 4; ++df) {
      bf16x8 vf = *(const bf16x8*)(Vp + (size_t)(16 * df + qcol) * S_ + kt + g * 8);
      o[df] = __builtin_amdgcn_mfma_f32_16x16x32_bf16(vf, bp.v, o[df], 0, 0, 0);
    }
  }
  lsum += __shfl_xor(lsum, 16);
  lsum += __shfl_xor(lsum, 32);
  const float inv = 1.f / lsum;
  bf16* Op = O + (size_t)(b * S_ + q) * (NH_ * HD_) + h * HD_;
  #pragma unroll
  for (int df = 0; df < 4; ++df) {
    ushort4 st = { f2bf(o[df][0] * inv), f2bf(o[df][1] * inv),
                   f2bf(o[df][2] * inv), f2bf(o[df][3] * inv) };
    *(ushort4*)((unsigned short*)Op + 16 * df + 4 * g) = st;
  }
}

// ---------------- MoE FFN1: 128x64 tile, dual-B, counted-vmcnt 2-phase ----------------
__global__ __launch_bounds__(256)
void moe_ffn1_kernel(const bf16* __restrict__ X, const bf16* __restrict__ W1t,
                     const bf16* __restrict__ W3t,
                     const int* __restrict__ counts, const int* __restrict__ entries,
                     bf16* __restrict__ Hb) {
  const int e = blockIdx.z;
  const int n_e = counts[e];
  const int r0 = blockIdx.y * 128;
  if (r0 >= n_e) return;
  const int f0 = blockIdx.x * 64;
  __shared__ char Al[2][8192], B1l[2][4096], B3l[2][4096];
  __shared__ int rowent[128];
  const int t = threadIdx.x;
  if (t < 128) { int r = r0 + t; rowent[t] = (r < n_e) ? entries[e * T_ + r] : -1; }
  __syncthreads();
  const int lane = t & 63, wid = t >> 6, wr = wid >> 1, wc = wid & 1;
  const int sr = t >> 2, sc = t & 3;
  const int c0 = sc ^ ((sr >> 1) & 3);
  const int c1 = sc ^ (((sr + 64) >> 1) & 3);
  int ea = rowent[sr], eb = rowent[sr + 64];
  const bf16* gA0 = X + (size_t)(ea < 0 ? 0 : (ea >> 1)) * H_ + c0 * 8;
  const bf16* gA1 = X + (size_t)(eb < 0 ? 0 : (eb >> 1)) * H_ + c1 * 8;
  const bf16* W1b = W1t + (size_t)e * F_ * H_;  // [F][H]
  const bf16* W3b = W3t + (size_t)e * F_ * H_;
  const bf16* gB1 = W1b + (size_t)(f0 + sr) * H_ + c0 * 8;
  const bf16* gB3 = W3b + (size_t)(f0 + sr) * H_ + c0 * 8;
  const int la = lane & 15, kg = lane >> 4;
  const int swz = (kg ^ ((la >> 1) & 3)) * 16;
  const int aoff = (wr * 64 + la) * 64 + swz;
  const int boff = (wc * 32 + la) * 64 + swz;
  auto STAGE = [&](int buf, int k0) {
    stage16(gA0 + k0, Al[buf] + t * 16);
    stage16(gA1 + k0, Al[buf] + 4096 + t * 16);
    stage16(gB1 + k0, B1l[buf] + t * 16);
    stage16(gB3 + k0, B3l[buf] + t * 16);
  };
  f32x4 acc1[4][2] = {}, acc3[4][2] = {};
  STAGE(0, 0);
  for (int k0 = 0; k0 < H_; k0 += 32) {
    const int cur = (k0 >> 5) & 1;
    if (k0 + 32 < H_) {
      STAGE(cur ^ 1, k0 + 32);
      asm volatile("s_waitcnt vmcnt(4)" ::: "memory");
    } else {
      asm volatile("s_waitcnt vmcnt(0)" ::: "memory");
    }
    __builtin_amdgcn_s_barrier();
    bf16x8 af[4], b1f[2], b3f[2];
    #pragma unroll
    for (int i = 0; i < 4; ++i) af[i] = *(const bf16x8*)(Al[cur] + aoff + i * 1024);
    #pragma unroll
    for (int i = 0; i < 2; ++i) b1f[i] = *(const bf16x8*)(B1l[cur] + boff + i * 1024);
    #pragma unroll
    for (int i = 0; i < 2; ++i) b3f[i] = *(const bf16x8*)(B3l[cur] + boff + i * 1024);
    #pragma unroll
    for (int mi = 0; mi < 4; ++mi)
      #pragma unroll
      for (int ni = 0; ni < 2; ++ni) {
        acc1[mi][ni] = __builtin_amdgcn_mfma_f32_16x16x32_bf16(af[mi], b1f[ni], acc1[mi][ni], 0, 0, 0);
        acc3[mi][ni] = __builtin_amdgcn_mfma_f32_16x16x32_bf16(af[mi], b3f[ni], acc3[mi][ni], 0, 0, 0);
      }
    __builtin_amdgcn_s_barrier();
  }
  #pragma unroll
  for (int mi = 0; mi < 4; ++mi) {
    int rloc = wr * 64 + mi * 16 + kg * 4;
    #pragma unroll
    for (int ni = 0; ni < 2; ++ni) {
      int col = f0 + wc * 32 + ni * 16 + la;
      #pragma unroll
      for (int r = 0; r < 4; ++r) {
        int ent = rowent[rloc + r];
        if (ent < 0) continue;
        float gv = acc1[mi][ni][r], uv = acc3[mi][ni][r];
        Hb[(size_t)ent * F_ + col] = __float2bfloat16(silu_f(gv) * uv);
      }
    }
  }
}

// ---------------- MoE FFN2: 128x64 tile, counted-vmcnt 2-phase ----------------
__global__ __launch_bounds__(256)
void moe_ffn2_kernel(const bf16* __restrict__ Hb, const bf16* __restrict__ W2t,
                     const int* __restrict__ counts, const int* __restrict__ entries,
                     float* __restrict__ Y) {
  const int e = blockIdx.z;
  const int n_e = counts[e];
  const int r0 = blockIdx.y * 128;
  if (r0 >= n_e) return;
  const int n0 = blockIdx.x * 64;
  __shared__ char Al[2][8192], Bl[2][4096];
  __shared__ int rowent[128];
  const int t = threadIdx.x;
  if (t < 128) { int r = r0 + t; rowent[t] = (r < n_e) ? entries[e * T_ + r] : -1; }
  __syncthreads();
  const int lane = t & 63, wid = t >> 6, wr = wid >> 1, wc = wid & 1;
  const int sr = t >> 2, sc = t & 3;
  const int c0 = sc ^ ((sr >> 1) & 3);
  const int c1 = sc ^ (((sr + 64) >> 1) & 3);
  int ea = rowent[sr], eb = rowent[sr + 64];
  const bf16* gA0 = Hb + (size_t)(ea < 0 ? 0 : ea) * F_ + c0 * 8;
  const bf16* gA1 = Hb + (size_t)(eb < 0 ? 0 : eb) * F_ + c1 * 8;
  const bf16* W2b = W2t + (size_t)e * H_ * F_;  // [H][F]
  const bf16* gB0 = W2b + (size_t)(n0 + sr) * F_ + c0 * 8;
  const int la = lane & 15, kg = lane >> 4;
  const int swz = (kg ^ ((la >> 1) & 3)) * 16;
  const int aoff = (wr * 64 + la) * 64 + swz;
  const int boff = (wc * 32 + la) * 64 + swz;
  auto STAGE = [&](int buf, int k0) {
    stage16(gA0 + k0, Al[buf] + t * 16);
    stage16(gA1 + k0, Al[buf] + 4096 + t * 16);
    stage16(gB0 + k0, Bl[buf] + t * 16);
  };
  f32x4 acc[4][2] = {};
  STAGE(0, 0);
  for (int k0 = 0; k0 < F_; k0 += 32) {
    const int cur = (k0 >> 5) & 1;
    if (k0 + 32 < F_) {
      STAGE(cur ^ 1, k0 + 32);
      asm volatile("s_waitcnt vmcnt(3)" ::: "memory");
    } else {
      asm volatile("s_waitcnt vmcnt(0)" ::: "memory");
    }
    __builtin_amdgcn_s_barrier();
    bf16x8 af[4], bfr[2];
    #pragma unroll
    for (int i = 0; i < 4; ++i) af[i] = *(const bf16x8*)(Al[cur] + aoff + i * 1024);
    #pragma unroll
    for (int i = 0; i < 2; ++i) bfr[i] = *(const bf16x8*)(Bl[cur] + boff + i * 1024);
    #pragma unroll
    for (int mi = 0; mi < 4; ++mi)
      #pragma unroll
      for (int ni = 0; ni < 2; ++ni)
        acc[mi][ni] = __builtin_amdgcn_mfma_f32_16x16x32_bf16(af[mi], bfr[ni], acc[mi][ni], 0, 0, 0);
    __builtin_amdgcn_s_barrier();
  }
  #pragma unroll
  for (int mi = 0; mi < 4; ++mi) {
    int rloc = wr * 64 + mi * 16 + kg * 4;
    #pragma unroll
    for (int ni = 0; ni < 2; ++ni) {
      int col = n0 + wc * 32 + ni * 16 + la;
      #pragma unroll
      for (int r = 0; r < 4; ++r) {
        int ent = rowent[rloc + r];
        if (ent < 0) continue;
        Y[(size_t)ent * H_ + col] = acc[mi][ni][r];
      }
    }
  }
}

// ---------------- combine: out[t] += w0*Y[2t] + w1*Y[2t+1] ----------------
__global__ void combine_kernel(const float* __restrict__ Y, const float* __restrict__ wgt,
                               float* __restrict__ out) {
  int t = blockIdx.x;
  int c = threadIdx.x;  // 256
  float w0 = wgt[t * 2], w1 = wgt[t * 2 + 1];
  float4 y0 = *(const float4*)(&Y[((size_t)t * 2) * H_ + c * 4]);
  float4 y1 = *(const float4*)(&Y[((size_t)t * 2 + 1) * H_ + c * 4]);
  float4 o  = *(float4*)(&out[(size_t)t * H_ + c * 4]);
  o.x += w0 * y0.x + w1 * y1.x;
  o.y += w0 * y0.y + w1 * y1.y;
  o.z += w0 * y0.z + w1 * y1.z;
  o.w += w0 * y0.w + w1 * y1.w;
  *(float4*)(&out[(size_t)t * H_ + c * 4]) = o;
}

extern "C" void kernel_launch(void* const* d_in, const int* in_sizes, int n_in,
                              void* d_out, int out_size, void* d_ws, size_t ws_size,
                              hipStream_t stream) {
  const float* hidden    = (const float*)d_in[0];
  const float* ln1_w     = (const float*)d_in[1];
  const float* q_w       = (const float*)d_in[2];
  const float* k_w       = (const float*)d_in[3];
  const float* v_w       = (const float*)d_in[4];
  const float* o_w       = (const float*)d_in[5];
  const float* res_ln_w  = (const float*)d_in[6];
  const float* rw1       = (const float*)d_in[7];
  const float* rw3       = (const float*)d_in[8];
  const float* rw2       = (const float*)d_in[9];
  const float* post_ln_w = (const float*)d_in[10];
  const float* gate_w    = (const float*)d_in[11];
  const float* e_w1      = (const float*)d_in[12];
  const float* e_w3      = (const float*)d_in[13];
  const float* e_w2      = (const float*)d_in[14];
  float* out = (float*)d_out;

  char* base = (char*)d_ws;
  size_t off = 0;
  auto alloc = [&](size_t bytes) -> void* {
    void* p = base + off;
    off += (bytes + 255) & ~(size_t)255;
    return p;
  };
  float* qkvf   = (float*)alloc((size_t)T_ * QKVN_ * 4);
  float* costab = (float*)alloc((size_t)S_ * 32 * 4);
  float* sintab = (float*)alloc((size_t)S_ * 32 * 4);
  float* resat  = (float*)alloc((size_t)T_ * H_ * 4);
  float* wgt    = (float*)alloc((size_t)T_ * 2 * 4);
  float* Y      = (float*)alloc((size_t)T_ * 2 * H_ * 4);
  bf16* h1b     = (bf16*)alloc((size_t)T_ * H_ * 2);
  bf16* h2b     = (bf16*)alloc((size_t)T_ * H_ * 2);
  bf16* h3b     = (bf16*)alloc((size_t)T_ * H_ * 2);
  bf16* attnb   = (bf16*)alloc((size_t)T_ * H_ * 2);
  bf16* gb      = (bf16*)alloc((size_t)T_ * H_ * 2);
  bf16* Hb      = (bf16*)alloc((size_t)T_ * 2 * F_ * 2);
  bf16* Qbuf    = (bf16*)alloc((size_t)B_ * NH_ * S_ * HD_ * 2);
  bf16* Kbuf    = (bf16*)alloc((size_t)B_ * NKV_ * S_ * HD_ * 2);
  bf16* Vtbuf   = (bf16*)alloc((size_t)B_ * NKV_ * HD_ * S_ * 2);
  bf16* qkvwt   = (bf16*)alloc((size_t)QKVN_ * H_ * 2);
  bf16* owt     = (bf16*)alloc((size_t)H_ * H_ * 2);
  bf16* w13t    = (bf16*)alloc((size_t)2048 * H_ * 2);
  bf16* rw2t    = (bf16*)alloc((size_t)H_ * H_ * 2);
  bf16* ew1t    = (bf16*)alloc((size_t)E_ * F_ * H_ * 2);
  bf16* ew3t    = (bf16*)alloc((size_t)E_ * F_ * H_ * 2);
  bf16* ew2t    = (bf16*)alloc((size_t)E_ * H_ * F_ * 2);
  int* counts   = (int*)alloc(64);
  int* entries  = (int*)alloc((size_t)E_ * T_ * 4);

  rope_table_kernel<<<(S_ * 32 + 255) / 256, 256, 0, stream>>>(costab, sintab, counts);

  // weight prep: fp32 [K][N] -> bf16 [N][K]; five 1024x1024 in ONE launch
  {
    TransBatch tb;
    tb.src[0] = q_w;  tb.dst[0] = qkvwt;
    tb.src[1] = o_w;  tb.dst[1] = owt;
    tb.src[2] = rw1;  tb.dst[2] = w13t;
    tb.src[3] = rw3;  tb.dst[3] = w13t + (size_t)1024 * 1024;
    tb.src[4] = rw2;  tb.dst[4] = rw2t;
    transpose_cvt5_kernel<<<dim3(32, 32, 5), 256, 0, stream>>>(tb, 1024, 1024);
  }
  {
    TransBatch tb = {};
    tb.src[0] = k_w;  tb.dst[0] = qkvwt + (size_t)1024 * 1024;
    tb.src[1] = v_w;  tb.dst[1] = qkvwt + (size_t)1280 * 1024;
    transpose_cvt5_kernel<<<dim3(32, 8, 2), 256, 0, stream>>>(tb, 1024, 256);
  }
  transpose_cvt_kernel<<<dim3(32, 88, 8), 256, 0, stream>>>(e_w1, ew1t, 1024, 2816);
  transpose_cvt_kernel<<<dim3(32, 88, 8), 256, 0, stream>>>(e_w3, ew3t, 1024, 2816);
  transpose_cvt_kernel<<<dim3(88, 32, 8), 256, 0, stream>>>(e_w2, ew2t, 2816, 1024);

  // attention path
  rms_kernel<<<T_, 256, 0, stream>>>(hidden, ln1_w, h1b);
  mm_kernel<64, false><<<dim3(QKVN_ / 64, T_ / 128), 256, 0, stream>>>(h1b, qkvwt, nullptr, qkvf, T_, QKVN_, H_);
  rope_cvt_qk_kernel<<<(T_ * 20 * 32) / 256, 256, 0, stream>>>(qkvf, costab, sintab, Qbuf, Kbuf);
  vt_kernel<<<dim3(32, 2, 8), 256, 0, stream>>>(qkvf, Vtbuf);
  attn_kernel<<<dim3(S_ / 64, NH_, B_), 256, 0, stream>>>(Qbuf, Kbuf, Vtbuf, attnb);
  mm_kernel<64, true><<<dim3(16, 16), 256, 0, stream>>>(attnb, owt, hidden, resat, T_, H_, H_);

  // parallel residual dense MLP (fused w13 GEMM + silu*mul)
  rms_kernel<<<T_, 256, 0, stream>>>(resat, res_ln_w, h2b);
  mlp13_kernel<<<dim3(16, 16), 256, 0, stream>>>(h2b, w13t, gb);
  mm_kernel<64, true><<<dim3(16, 16), 256, 0, stream>>>(gb, rw2t, resat, out, T_, H_, H_);

  // MoE path on the ORIGINAL layer input (fused RMS + gate)
  rms_gate_kernel<<<T_, 256, 0, stream>>>(hidden, post_ln_w, gate_w, h3b, counts, entries, wgt);
  moe_ffn1_kernel<<<dim3(F_ / 64, 16, E_), 256, 0, stream>>>(h3b, ew1t, ew3t, counts, entries, Hb);
  moe_ffn2_kernel<<<dim3(H_ / 64, 16, E_), 256, 0, stream>>>(Hb, ew2t, counts, entries, Y);
  combine_kernel<<<T_, 256, 0, stream>>>(Y, wgt, out);
}